// Round 2
// baseline (6166.509 us; speedup 1.0000x reference)
//
#include <hip/hip_runtime.h>
#include <math.h>

#define Bdim 8
#define Ldim 1024
#define DEC_IN 7
#define D_MODEL 512
#define MARK 4
#define D_INNER 1024
#define D_STATE 16
#define D_CONV 4
#define DT_RANK 32
#define N_HEADS 8
#define DH 64
#define ROWS (Bdim*Ldim)   // 8192

// ---------------- embed: token circular conv3 + pos embed + mark proj ----------------
__global__ void embed_kernel(const float* __restrict__ xd, const float* __restrict__ xmark,
                             const float* __restrict__ token_w, const float* __restrict__ temp_w,
                             float* __restrict__ x) {
    int bt = blockIdx.x;            // 0..8191
    int b = bt >> 10, t = bt & 1023;
    __shared__ float xr[3][DEC_IN];
    __shared__ float mk[MARK];
    if (threadIdx.x < 3*DEC_IN) {
        int k = threadIdx.x / DEC_IN, c = threadIdx.x % DEC_IN;
        int tt = (t + k - 1 + Ldim) % Ldim;
        xr[k][c] = xd[((size_t)b*Ldim + tt)*DEC_IN + c];
    }
    if (threadIdx.x < MARK) mk[threadIdx.x] = xmark[((size_t)b*Ldim + t)*MARK + threadIdx.x];
    __syncthreads();
    for (int dd = threadIdx.x; dd < D_MODEL; dd += 256) {
        float acc = 0.f;
        #pragma unroll
        for (int k = 0; k < 3; ++k)
            #pragma unroll
            for (int c = 0; c < DEC_IN; ++c)
                acc += xr[k][c] * token_w[(k*DEC_IN + c)*D_MODEL + dd];
        int i2 = dd & ~1;
        float freq = expf(-(float)i2 * (logf(10000.f) / (float)D_MODEL));
        float ang = (float)t * freq;
        acc += (dd & 1) ? cosf(ang) : sinf(ang);
        #pragma unroll
        for (int m = 0; m < MARK; ++m) acc += mk[m] * temp_w[m*D_MODEL + dd];
        x[(size_t)bt*D_MODEL + dd] = acc;
    }
}

// ---------------- generic fp32 GEMM: C = A@W (+bias) (+softplus) ----------------
// BM=BN=128, BK=8, 256 threads, 8x8 per thread.
template<int ACT>  // 0=none, 1=softplus
__global__ __launch_bounds__(256) void gemm_f32(const float* __restrict__ A, int lda,
                                                const float* __restrict__ W, int ldw,
                                                const float* __restrict__ bias,
                                                float* __restrict__ C, int ldc,
                                                int M, int N, int K) {
    __shared__ float As[8][128];
    __shared__ float Bs[8][128];
    int bm = blockIdx.y * 128;
    int bn = blockIdx.x * 128;
    int tx = threadIdx.x & 15, ty = threadIdx.x >> 4;
    bool wAligned = ((ldw & 3) == 0);

    float acc[8][8];
    #pragma unroll
    for (int i = 0; i < 8; ++i)
        #pragma unroll
        for (int j = 0; j < 8; ++j) acc[i][j] = 0.f;

    int arow = threadIdx.x >> 1;
    int ak4  = (threadIdx.x & 1) * 4;
    int bkrow = threadIdx.x >> 5;
    int bcol  = (threadIdx.x & 31) * 4;

    for (int k0 = 0; k0 < K; k0 += 8) {
        __syncthreads();
        // A tile (always aligned: lda%4==0, K%8==0)
        {
            float4 av = *(const float4*)(A + (size_t)(bm + arow)*lda + k0 + ak4);
            As[ak4+0][arow] = av.x;
            As[ak4+1][arow] = av.y;
            As[ak4+2][arow] = av.z;
            As[ak4+3][arow] = av.w;
        }
        // W tile
        {
            const float* wp = W + (size_t)(k0 + bkrow)*ldw + bn + bcol;
            float4 bv;
            if (wAligned && (bn + bcol + 3 < N)) {
                bv = *(const float4*)wp;
            } else {
                bv.x = (bn+bcol+0 < N) ? wp[0] : 0.f;
                bv.y = (bn+bcol+1 < N) ? wp[1] : 0.f;
                bv.z = (bn+bcol+2 < N) ? wp[2] : 0.f;
                bv.w = (bn+bcol+3 < N) ? wp[3] : 0.f;
            }
            *(float4*)&Bs[bkrow][bcol] = bv;
        }
        __syncthreads();
        #pragma unroll
        for (int k = 0; k < 8; ++k) {
            float4 a0 = *(const float4*)&As[k][ty*4];
            float4 a1 = *(const float4*)&As[k][64 + ty*4];
            float4 b0 = *(const float4*)&Bs[k][tx*4];
            float4 b1 = *(const float4*)&Bs[k][64 + tx*4];
            float a[8] = {a0.x,a0.y,a0.z,a0.w,a1.x,a1.y,a1.z,a1.w};
            float bb[8] = {b0.x,b0.y,b0.z,b0.w,b1.x,b1.y,b1.z,b1.w};
            #pragma unroll
            for (int i = 0; i < 8; ++i)
                #pragma unroll
                for (int j = 0; j < 8; ++j)
                    acc[i][j] = fmaf(a[i], bb[j], acc[i][j]);
        }
    }
    #pragma unroll
    for (int i = 0; i < 8; ++i) {
        int r = bm + ((i < 4) ? (ty*4 + i) : (64 + ty*4 + i - 4));
        if (r >= M) continue;
        #pragma unroll
        for (int j = 0; j < 8; ++j) {
            int c = bn + ((j < 4) ? (tx*4 + j) : (64 + tx*4 + j - 4));
            if (c >= N) continue;
            float v = acc[i][j];
            if (bias) v += bias[c];
            if (ACT == 1) v = (v > 20.f) ? v : log1pf(expf(v));
            C[(size_t)r*ldc + c] = v;
        }
    }
}

// ---------------- causal conv1d (k=4, per-channel) + SiLU ----------------
__global__ void conv_silu_kernel(const float* __restrict__ xz, const float* __restrict__ conv_w,
                                 const float* __restrict__ conv_b, float* __restrict__ uc) {
    int idx = blockIdx.x * 256 + threadIdx.x;    // over B*L*D_INNER
    if (idx >= Bdim*Ldim*D_INNER) return;
    int d = idx & 1023;
    int bt = idx >> 10;
    int t = bt & 1023, b = bt >> 10;
    const float* u = xz + (size_t)b*Ldim*2048;   // u part = cols [0,1024)
    float acc = conv_b[d];
    #pragma unroll
    for (int k = 0; k < 4; ++k) {
        int tt = t + k - 3;
        if (tt >= 0) acc = fmaf(u[(size_t)tt*2048 + d], conv_w[d*4 + k], acc);
    }
    uc[idx] = acc / (1.f + expf(-acc));
}

// ---------------- selective scan: one thread per (b,d) ----------------
__global__ __launch_bounds__(64) void scan_kernel(const float* __restrict__ delta,
                                                  const float* __restrict__ uc,
                                                  const float* __restrict__ dbc,
                                                  const float* __restrict__ A_log,
                                                  float* __restrict__ ys) {
    int gid = blockIdx.x * 64 + threadIdx.x;   // 0..8191
    int d = gid & 1023, b = gid >> 10;
    float A[D_STATE], h[D_STATE];
    #pragma unroll
    for (int s = 0; s < D_STATE; ++s) { A[s] = -expf(A_log[d*D_STATE + s]); h[s] = 0.f; }
    const float* dptr = delta + (size_t)b*Ldim*D_INNER + d;
    const float* uptr = uc    + (size_t)b*Ldim*D_INNER + d;
    const float* bc   = dbc   + (size_t)b*Ldim*64;
    float* yp = ys + (size_t)b*Ldim*D_INNER + d;
    for (int t = 0; t < Ldim; ++t) {
        float dl = dptr[(size_t)t*D_INNER];
        float ut = uptr[(size_t)t*D_INNER];
        float du = dl * ut;
        float y = 0.f;
        #pragma unroll
        for (int s = 0; s < D_STATE; ++s) {
            float e = expf(dl * A[s]);
            float Bv = bc[t*64 + DT_RANK + s];
            float Cv = bc[t*64 + DT_RANK + D_STATE + s];
            h[s] = fmaf(e, h[s], du * Bv);
            y = fmaf(h[s], Cv, y);
        }
        yp[(size_t)t*D_INNER] = y;
    }
}

// ---------------- y = (ys + uc*D_skip) * silu(z) ----------------
__global__ void combine_kernel(const float* __restrict__ xz, const float* __restrict__ uc,
                               const float* __restrict__ D_skip, float* __restrict__ ys) {
    int idx = blockIdx.x * 256 + threadIdx.x;
    if (idx >= Bdim*Ldim*D_INNER) return;
    int d = idx & 1023;
    int bt = idx >> 10;
    float z = xz[(size_t)bt*2048 + 1024 + d];
    float y = fmaf(uc[idx], D_skip[d], ys[idx]);
    ys[idx] = y * (z / (1.f + expf(-z)));
}

// ---------------- fused residual + LayerNorm (wave per row) ----------------
__global__ __launch_bounds__(256) void ln_kernel(float* __restrict__ x, const float* __restrict__ t,
                                                 const float* __restrict__ g, const float* __restrict__ bta) {
    int row = blockIdx.x * 4 + (threadIdx.x >> 6);
    int lane = threadIdx.x & 63;
    const float* xr = x + (size_t)row*D_MODEL;
    const float* tr = t + (size_t)row*D_MODEL;
    float v[8];
    float sum = 0.f;
    #pragma unroll
    for (int j = 0; j < 8; ++j) { v[j] = xr[lane + j*64] + tr[lane + j*64]; sum += v[j]; }
    #pragma unroll
    for (int off = 32; off; off >>= 1) sum += __shfl_xor(sum, off);
    float mu = sum * (1.f/512.f);
    float vs = 0.f;
    #pragma unroll
    for (int j = 0; j < 8; ++j) { float dm = v[j] - mu; vs += dm*dm; }
    #pragma unroll
    for (int off = 32; off; off >>= 1) vs += __shfl_xor(vs, off);
    float inv = rsqrtf(vs * (1.f/512.f) + 1e-5f);
    #pragma unroll
    for (int j = 0; j < 8; ++j) {
        int c = lane + j*64;
        x[(size_t)row*D_MODEL + c] = (v[j] - mu) * inv * g[c] + bta[c];
    }
}

// ---------------- causal flash attention, fp32, wave per query ----------------
__global__ __launch_bounds__(256) void attn_kernel(const float* __restrict__ q, const float* __restrict__ k,
                                                   const float* __restrict__ v, float* __restrict__ o) {
    int b = blockIdx.z, h = blockIdx.y;
    int wave = threadIdx.x >> 6, lane = threadIdx.x & 63;
    int tq = blockIdx.x * 4 + wave;
    __shared__ float Kl[64][DH+1];
    __shared__ float Vl[64][DH+1];
    __shared__ float Ql[4][DH];
    const size_t base = ((size_t)b*Ldim)*D_MODEL + h*DH;
    Ql[wave][lane] = q[base + (size_t)tq*D_MODEL + lane] * 0.125f;
    float m = -INFINITY, l = 0.f, acc = 0.f;
    int ntiles = (blockIdx.x*4 + 3) / 64 + 1;
    for (int kt = 0; kt < ntiles; ++kt) {
        __syncthreads();
        for (int e = threadIdx.x; e < 64*64; e += 256) {
            int r = e >> 6, c = e & 63;
            Kl[r][c] = k[base + (size_t)(kt*64 + r)*D_MODEL + c];
            Vl[r][c] = v[base + (size_t)(kt*64 + r)*D_MODEL + c];
        }
        __syncthreads();
        float s = 0.f;
        #pragma unroll 16
        for (int dd = 0; dd < 64; ++dd) s = fmaf(Ql[wave][dd], Kl[lane][dd], s);
        int key = kt*64 + lane;
        if (key > tq) s = -INFINITY;
        float tm = s;
        #pragma unroll
        for (int off = 32; off; off >>= 1) tm = fmaxf(tm, __shfl_xor(tm, off));
        float nm = fmaxf(m, tm);
        float corr = (m == -INFINITY) ? 0.f : expf(m - nm);
        float p = expf(s - nm);      // s=-inf -> 0
        float tsum = p;
        #pragma unroll
        for (int off = 32; off; off >>= 1) tsum += __shfl_xor(tsum, off);
        l = l * corr + tsum;
        acc *= corr;
        #pragma unroll 8
        for (int j = 0; j < 64; ++j) {
            float pj = __shfl(p, j);
            acc = fmaf(pj, Vl[j][lane], acc);
        }
        m = nm;
    }
    o[base + (size_t)tq*D_MODEL + lane] = acc / l;
}

// ---------------- workspace layout (floats) ----------------
#define X_OFF      0u
#define XZ_OFF     4194304u
#define UC_OFF     20971520u
#define DBC_OFF    29360128u
#define DELTA_OFF  29884416u
#define YS_OFF     38273024u
#define WS_FLOATS  46661632u

extern "C" void kernel_launch(void* const* d_in, const int* in_sizes, int n_in,
                              void* d_out, int out_size, void* d_ws, size_t ws_size,
                              hipStream_t stream) {
    const float* x_dec   = (const float*)d_in[0];
    const float* x_mark  = (const float*)d_in[1];
    const float* token_w = (const float*)d_in[2];
    const float* temp_w  = (const float*)d_in[3];
    const float* in_proj_w = (const float*)d_in[4];
    const float* conv_w  = (const float*)d_in[5];
    const float* conv_b  = (const float*)d_in[6];
    const float* x_proj_w = (const float*)d_in[7];
    const float* dt_w    = (const float*)d_in[8];
    const float* dt_b    = (const float*)d_in[9];
    const float* A_log   = (const float*)d_in[10];
    const float* D_skip  = (const float*)d_in[11];
    const float* out_w_m = (const float*)d_in[12];
    const float* wq = (const float*)d_in[13];
    const float* bq = (const float*)d_in[14];
    const float* wk = (const float*)d_in[15];
    const float* bk = (const float*)d_in[16];
    const float* wv = (const float*)d_in[17];
    const float* bv = (const float*)d_in[18];
    const float* wo = (const float*)d_in[19];
    const float* bo = (const float*)d_in[20];
    const float* ln1_g = (const float*)d_in[21];
    const float* ln1_b = (const float*)d_in[22];
    const float* ln2_g = (const float*)d_in[23];
    const float* ln2_b = (const float*)d_in[24];
    const float* proj_w = (const float*)d_in[25];
    const float* proj_b = (const float*)d_in[26];

    if (ws_size < (size_t)WS_FLOATS * sizeof(float)) return;

    float* ws    = (float*)d_ws;
    float* x     = ws + X_OFF;
    float* xz    = ws + XZ_OFF;
    float* qb    = xz;                 // reuse xz region after z consumed
    float* kb    = xz + 4194304;
    float* vb    = xz + 8388608;
    float* ob    = xz + 12582912;
    float* uc    = ws + UC_OFF;
    float* dbc   = ws + DBC_OFF;
    float* delta = ws + DELTA_OFF;
    float* tmp   = delta;              // alias: delta dead when tmp used
    float* ys    = ws + YS_OFF;
    float* out   = (float*)d_out;

    embed_kernel<<<ROWS, 256, 0, stream>>>(x_dec, x_mark, token_w, temp_w, x);

    for (int i = 0; i < 2; ++i) {
        // xz = x @ in_proj_w[i]           (8192 x 2048 x 512)
        gemm_f32<0><<<dim3(16,64), 256, 0, stream>>>(x, 512, in_proj_w + (size_t)i*512*2048, 2048,
                                                     nullptr, xz, 2048, ROWS, 2048, 512);
        // uc = silu(causal_conv(u))
        conv_silu_kernel<<<(Bdim*Ldim*D_INNER)/256, 256, 0, stream>>>(xz, conv_w + i*D_INNER*D_CONV,
                                                                      conv_b + i*D_INNER, uc);
        // dbc = uc @ x_proj_w[i]          (8192 x 64 x 1024)
        gemm_f32<0><<<dim3(1,64), 256, 0, stream>>>(uc, 1024, x_proj_w + i*D_INNER*64, 64,
                                                    nullptr, dbc, 64, ROWS, 64, 1024);
        // delta = softplus(dt @ dt_w + dt_b)   (8192 x 1024 x 32)
        gemm_f32<1><<<dim3(8,64), 256, 0, stream>>>(dbc, 64, dt_w + i*DT_RANK*D_INNER, 1024,
                                                    dt_b + i*D_INNER, delta, 1024, ROWS, 1024, DT_RANK);
        // selective scan
        scan_kernel<<<ROWS/64, 64, 0, stream>>>(delta, uc, dbc, A_log + i*D_INNER*D_STATE, ys);
        // y = (ys + uc*D_skip) * silu(z)
        combine_kernel<<<(Bdim*Ldim*D_INNER)/256, 256, 0, stream>>>(xz, uc, D_skip + i*D_INNER, ys);
        // tmp = y @ out_w_m[i]            (8192 x 512 x 1024)
        gemm_f32<0><<<dim3(4,64), 256, 0, stream>>>(ys, 1024, out_w_m + (size_t)i*D_INNER*512, 512,
                                                    nullptr, tmp, 512, ROWS, 512, 1024);
        // x = LN(x + tmp)
        ln_kernel<<<ROWS/4, 256, 0, stream>>>(x, tmp, ln1_g + i*512, ln1_b + i*512);
        // q,k,v
        gemm_f32<0><<<dim3(4,64), 256, 0, stream>>>(x, 512, wq + (size_t)i*512*512, 512,
                                                    bq + i*512, qb, 512, ROWS, 512, 512);
        gemm_f32<0><<<dim3(4,64), 256, 0, stream>>>(x, 512, wk + (size_t)i*512*512, 512,
                                                    bk + i*512, kb, 512, ROWS, 512, 512);
        gemm_f32<0><<<dim3(4,64), 256, 0, stream>>>(x, 512, wv + (size_t)i*512*512, 512,
                                                    bv + i*512, vb, 512, ROWS, 512, 512);
        // attention
        attn_kernel<<<dim3(Ldim/4, N_HEADS, Bdim), 256, 0, stream>>>(qb, kb, vb, ob);
        // tmp = o @ wo + bo
        gemm_f32<0><<<dim3(4,64), 256, 0, stream>>>(ob, 512, wo + (size_t)i*512*512, 512,
                                                    bo + i*512, tmp, 512, ROWS, 512, 512);
        // x = LN(x + tmp)
        ln_kernel<<<ROWS/4, 256, 0, stream>>>(x, tmp, ln2_g + i*512, ln2_b + i*512);
    }
    // out = x @ proj_w + proj_b   (8192 x 7 x 512)
    gemm_f32<0><<<dim3(1,64), 256, 0, stream>>>(x, 512, proj_w, 7, proj_b, out, 7, ROWS, 7, 512);
}

// Round 3
// 2557.482 us; speedup vs baseline: 2.4112x; 2.4112x over previous
//
#include <hip/hip_runtime.h>
#include <math.h>

#define Bdim 8
#define Ldim 1024
#define DEC_IN 7
#define D_MODEL 512
#define MARK 4
#define D_INNER 1024
#define D_STATE 16
#define D_CONV 4
#define DT_RANK 32
#define N_HEADS 8
#define DH 64
#define ROWS (Bdim*Ldim)   // 8192
#define MB (1ull<<20)

typedef unsigned short u16;
typedef unsigned int u32;
typedef __attribute__((ext_vector_type(8))) short bf16x8;
typedef __attribute__((ext_vector_type(4))) float f32x4;
typedef __attribute__((ext_vector_type(4))) unsigned short u16x4;

__device__ inline float b2f(u16 u) {
    union { u32 i; float f; } c; c.i = ((u32)u) << 16; return c.f;
}
__device__ inline u16 f2b(float f) {
    union { float f; u32 u; } c; c.f = f;
    u32 u = c.u;
    u32 r = (u + 0x7fffu + ((u >> 16) & 1u)) >> 16;
    return (u16)r;
}

// ---------------- embed: token circular conv3 + pos embed + mark proj (dual f32/bf16 out) ----------------
__global__ void embed_kernel(const float* __restrict__ xd, const float* __restrict__ xmark,
                             const float* __restrict__ token_w, const float* __restrict__ temp_w,
                             float* __restrict__ x, u16* __restrict__ xbf) {
    int bt = blockIdx.x;            // 0..8191
    int b = bt >> 10, t = bt & 1023;
    __shared__ float xr[3][DEC_IN];
    __shared__ float mk[MARK];
    if (threadIdx.x < 3*DEC_IN) {
        int k = threadIdx.x / DEC_IN, c = threadIdx.x % DEC_IN;
        int tt = (t + k - 1 + Ldim) % Ldim;
        xr[k][c] = xd[((size_t)b*Ldim + tt)*DEC_IN + c];
    }
    if (threadIdx.x < MARK) mk[threadIdx.x] = xmark[((size_t)b*Ldim + t)*MARK + threadIdx.x];
    __syncthreads();
    for (int dd = threadIdx.x; dd < D_MODEL; dd += 256) {
        float acc = 0.f;
        #pragma unroll
        for (int k = 0; k < 3; ++k)
            #pragma unroll
            for (int c = 0; c < DEC_IN; ++c)
                acc += xr[k][c] * token_w[(k*DEC_IN + c)*D_MODEL + dd];
        int i2 = dd & ~1;
        float freq = expf(-(float)i2 * (logf(10000.f) / (float)D_MODEL));
        float ang = (float)t * freq;
        acc += (dd & 1) ? cosf(ang) : sinf(ang);
        #pragma unroll
        for (int m = 0; m < MARK; ++m) acc += mk[m] * temp_w[m*D_MODEL + dd];
        x[(size_t)bt*D_MODEL + dd] = acc;
        xbf[(size_t)bt*D_MODEL + dd] = f2b(acc);
    }
}

// ---------------- weight transpose + cast: W[K][N] f32 -> Wt[N][K] bf16 ----------------
__global__ __launch_bounds__(256) void transpose_cast(const float* __restrict__ W, u16* __restrict__ Wt,
                                                      int K, int N) {
    const float* Wz = W + (size_t)blockIdx.z * K * N;
    u16* Wtz = Wt + (size_t)blockIdx.z * K * N;
    __shared__ u16 tile[64][72];
    int k0 = blockIdx.y*64, n0 = blockIdx.x*64;
    int tid = threadIdx.x;
    #pragma unroll
    for (int it = 0; it < 16; ++it) {
        int idx = it*256 + tid; int kr = idx>>6, nc = idx&63;
        tile[kr][nc] = f2b(Wz[(size_t)(k0+kr)*N + n0 + nc]);
    }
    __syncthreads();
    #pragma unroll
    for (int it = 0; it < 2; ++it) {
        int idx = it*256 + tid; int nr = idx>>3, slot = idx&7;
        bf16x8 v;
        #pragma unroll
        for (int j = 0; j < 8; ++j) ((u16*)&v)[j] = tile[slot*8+j][nr];
        *(bf16x8*)(Wtz + (size_t)(n0+nr)*K + k0 + slot*8) = v;
    }
}

// ---------------- bf16 MFMA GEMM: C = A@Wt^T (+bias). A[M][K] bf16, Wt[N][K] bf16 ----------------
// 128x128 tile, BK=64, 256 thr (4 waves, each 64x64). XOR-swizzled LDS, ds_read_b128 frags.
// OUTMODE: 0 = f32 out, 1 = bf16 out, 2 = bf16 transposed out (vt[b][col][t], for V)
template<int OUTMODE>
__global__ __launch_bounds__(256) void gemm_bf16(const u16* __restrict__ A, const u16* __restrict__ Bt,
                                                 const float* __restrict__ bias, void* __restrict__ Cp,
                                                 int N, int K, int ldc) {
    __shared__ u16 As[128*64];
    __shared__ u16 Bs[128*64];
    int tid = threadIdx.x;
    int bm = blockIdx.y*128, bn = blockIdx.x*128;
    int lane = tid & 63, wv = tid >> 6;
    int rm = (wv & 1)*64, cn = (wv >> 1)*64;
    int l15 = lane & 15, g = lane >> 4;

    f32x4 acc[4][4] = {};

    for (int k0 = 0; k0 < K; k0 += 64) {
        __syncthreads();
        #pragma unroll
        for (int it = 0; it < 4; ++it) {
            int idx = it*256 + tid;
            int row = idx >> 3, slot = idx & 7;
            bf16x8 av = *(const bf16x8*)(A + (size_t)(bm+row)*K + k0 + slot*8);
            *(bf16x8*)((char*)As + row*128 + ((slot ^ (row&7)) << 4)) = av;
            bf16x8 bv = *(const bf16x8*)(Bt + (size_t)(bn+row)*K + k0 + slot*8);
            *(bf16x8*)((char*)Bs + row*128 + ((slot ^ (row&7)) << 4)) = bv;
        }
        __syncthreads();
        #pragma unroll
        for (int ks = 0; ks < 2; ++ks) {
            bf16x8 af[4], bfr[4];
            #pragma unroll
            for (int m = 0; m < 4; ++m) {
                int row = rm + m*16 + l15;
                af[m] = *(const bf16x8*)((const char*)As + row*128 + (((ks*4+g) ^ (row&7)) << 4));
                int col = cn + m*16 + l15;
                bfr[m] = *(const bf16x8*)((const char*)Bs + col*128 + (((ks*4+g) ^ (col&7)) << 4));
            }
            #pragma unroll
            for (int m = 0; m < 4; ++m)
                #pragma unroll
                for (int n = 0; n < 4; ++n)
                    acc[m][n] = __builtin_amdgcn_mfma_f32_16x16x32_bf16(af[m], bfr[n], acc[m][n], 0, 0, 0);
        }
    }

    float bv4[4];
    #pragma unroll
    for (int n = 0; n < 4; ++n) bv4[n] = bias ? bias[bn + cn + n*16 + l15] : 0.f;

    #pragma unroll
    for (int m = 0; m < 4; ++m) {
        #pragma unroll
        for (int n = 0; n < 4; ++n) {
            int col = bn + cn + n*16 + l15;
            #pragma unroll
            for (int r = 0; r < 4; ++r) {
                int row = bm + rm + m*16 + g*4 + r;
                float v = acc[m][n][r] + bv4[n];
                if (OUTMODE == 0) {
                    ((float*)Cp)[(size_t)row*ldc + col] = v;
                } else if (OUTMODE == 1) {
                    ((u16*)Cp)[(size_t)row*ldc + col] = f2b(v);
                } else {
                    int b = row >> 10, t = row & 1023;
                    ((u16*)Cp)[((size_t)(b*D_MODEL) + col)*Ldim + t] = f2b(v);
                }
            }
        }
    }
}

// ---------------- generic fp32 GEMM (small shapes: x_proj, dt, final proj) ----------------
template<int ACT>  // 0=none, 1=softplus
__global__ __launch_bounds__(256) void gemm_f32(const float* __restrict__ A, int lda,
                                                const float* __restrict__ W, int ldw,
                                                const float* __restrict__ bias,
                                                float* __restrict__ C, int ldc,
                                                int M, int N, int K) {
    __shared__ float As[8][128];
    __shared__ float Bs[8][128];
    int bm = blockIdx.y * 128;
    int bn = blockIdx.x * 128;
    int tx = threadIdx.x & 15, ty = threadIdx.x >> 4;
    bool wAligned = ((ldw & 3) == 0);

    float acc[8][8];
    #pragma unroll
    for (int i = 0; i < 8; ++i)
        #pragma unroll
        for (int j = 0; j < 8; ++j) acc[i][j] = 0.f;

    int arow = threadIdx.x >> 1;
    int ak4  = (threadIdx.x & 1) * 4;
    int bkrow = threadIdx.x >> 5;
    int bcol  = (threadIdx.x & 31) * 4;

    for (int k0 = 0; k0 < K; k0 += 8) {
        __syncthreads();
        {
            float4 av = *(const float4*)(A + (size_t)(bm + arow)*lda + k0 + ak4);
            As[ak4+0][arow] = av.x;
            As[ak4+1][arow] = av.y;
            As[ak4+2][arow] = av.z;
            As[ak4+3][arow] = av.w;
        }
        {
            const float* wp = W + (size_t)(k0 + bkrow)*ldw + bn + bcol;
            float4 bv;
            if (wAligned && (bn + bcol + 3 < N)) {
                bv = *(const float4*)wp;
            } else {
                bv.x = (bn+bcol+0 < N) ? wp[0] : 0.f;
                bv.y = (bn+bcol+1 < N) ? wp[1] : 0.f;
                bv.z = (bn+bcol+2 < N) ? wp[2] : 0.f;
                bv.w = (bn+bcol+3 < N) ? wp[3] : 0.f;
            }
            *(float4*)&Bs[bkrow][bcol] = bv;
        }
        __syncthreads();
        #pragma unroll
        for (int k = 0; k < 8; ++k) {
            float4 a0 = *(const float4*)&As[k][ty*4];
            float4 a1 = *(const float4*)&As[k][64 + ty*4];
            float4 b0 = *(const float4*)&Bs[k][tx*4];
            float4 b1 = *(const float4*)&Bs[k][64 + tx*4];
            float a[8] = {a0.x,a0.y,a0.z,a0.w,a1.x,a1.y,a1.z,a1.w};
            float bb[8] = {b0.x,b0.y,b0.z,b0.w,b1.x,b1.y,b1.z,b1.w};
            #pragma unroll
            for (int i = 0; i < 8; ++i)
                #pragma unroll
                for (int j = 0; j < 8; ++j)
                    acc[i][j] = fmaf(a[i], bb[j], acc[i][j]);
        }
    }
    #pragma unroll
    for (int i = 0; i < 8; ++i) {
        int r = bm + ((i < 4) ? (ty*4 + i) : (64 + ty*4 + i - 4));
        if (r >= M) continue;
        #pragma unroll
        for (int j = 0; j < 8; ++j) {
            int c = bn + ((j < 4) ? (tx*4 + j) : (64 + tx*4 + j - 4));
            if (c >= N) continue;
            float v = acc[i][j];
            if (bias) v += bias[c];
            if (ACT == 1) v = (v > 20.f) ? v : log1pf(expf(v));
            C[(size_t)r*ldc + c] = v;
        }
    }
}

// ---------------- causal conv1d (k=4) + SiLU, bf16 in, dual f32/bf16 out ----------------
__global__ void conv_silu_kernel(const u16* __restrict__ xz, const float* __restrict__ conv_w,
                                 const float* __restrict__ conv_b,
                                 float* __restrict__ uc, u16* __restrict__ ucb) {
    int idx = blockIdx.x * 256 + threadIdx.x;    // over B*L*D_INNER
    if (idx >= Bdim*Ldim*D_INNER) return;
    int d = idx & 1023;
    int bt = idx >> 10;
    int t = bt & 1023, b = bt >> 10;
    float acc = conv_b[d];
    #pragma unroll
    for (int k = 0; k < 4; ++k) {
        int tt = t + k - 3;
        if (tt >= 0) acc = fmaf(b2f(xz[((size_t)(b*Ldim + tt))*2048 + d]), conv_w[d*4 + k], acc);
    }
    float s = acc / (1.f + expf(-acc));
    uc[idx] = s;
    ucb[idx] = f2b(s);
}

// ---------------- selective scan + skip + silu(z) gate fused, bf16 out ----------------
__global__ __launch_bounds__(64) void scan_kernel(const float* __restrict__ delta,
                                                  const float* __restrict__ uc,
                                                  const float* __restrict__ dbc,
                                                  const float* __restrict__ A_log,
                                                  const u16* __restrict__ xz,
                                                  const float* __restrict__ Dskip,
                                                  u16* __restrict__ ysb) {
    int gid = blockIdx.x * 64 + threadIdx.x;   // 0..8191
    int d = gid & 1023, b = gid >> 10;
    float A[D_STATE], h[D_STATE];
    #pragma unroll
    for (int s = 0; s < D_STATE; ++s) { A[s] = -expf(A_log[d*D_STATE + s]); h[s] = 0.f; }
    float Dk = Dskip[d];
    const float* dptr = delta + (size_t)b*Ldim*D_INNER + d;
    const float* uptr = uc    + (size_t)b*Ldim*D_INNER + d;
    const float* bc   = dbc   + (size_t)b*Ldim*64;
    const u16*   zp   = xz    + (size_t)b*Ldim*2048 + 1024 + d;
    u16* yp = ysb + (size_t)b*Ldim*D_INNER + d;
    for (int t = 0; t < Ldim; ++t) {
        float dl = dptr[(size_t)t*D_INNER];
        float ut = uptr[(size_t)t*D_INNER];
        float du = dl * ut;
        float y = 0.f;
        #pragma unroll
        for (int s = 0; s < D_STATE; ++s) {
            float e = __expf(dl * A[s]);
            float Bv = bc[t*64 + DT_RANK + s];
            float Cv = bc[t*64 + DT_RANK + D_STATE + s];
            h[s] = fmaf(e, h[s], du * Bv);
            y = fmaf(h[s], Cv, y);
        }
        float z = b2f(zp[(size_t)t*2048]);
        float yy = fmaf(ut, Dk, y);
        yp[(size_t)t*D_INNER] = f2b(yy * (z / (1.f + __expf(-z))));
    }
}

// ---------------- fused residual + LayerNorm, dual f32/bf16 out ----------------
__global__ __launch_bounds__(256) void ln_kernel(float* __restrict__ x, const float* __restrict__ t,
                                                 const float* __restrict__ g, const float* __restrict__ bta,
                                                 u16* __restrict__ xbf) {
    int row = blockIdx.x * 4 + (threadIdx.x >> 6);
    int lane = threadIdx.x & 63;
    const float* xr = x + (size_t)row*D_MODEL;
    const float* tr = t + (size_t)row*D_MODEL;
    float v[8];
    float sum = 0.f;
    #pragma unroll
    for (int j = 0; j < 8; ++j) { v[j] = xr[lane + j*64] + tr[lane + j*64]; sum += v[j]; }
    #pragma unroll
    for (int off = 32; off; off >>= 1) sum += __shfl_xor(sum, off);
    float mu = sum * (1.f/512.f);
    float vs = 0.f;
    #pragma unroll
    for (int j = 0; j < 8; ++j) { float dm = v[j] - mu; vs += dm*dm; }
    #pragma unroll
    for (int off = 32; off; off >>= 1) vs += __shfl_xor(vs, off);
    float inv = rsqrtf(vs * (1.f/512.f) + 1e-5f);
    #pragma unroll
    for (int j = 0; j < 8; ++j) {
        int c = lane + j*64;
        float o = (v[j] - mu) * inv * g[c] + bta[c];
        x[(size_t)row*D_MODEL + c] = o;
        xbf[(size_t)row*D_MODEL + c] = f2b(o);
    }
}

// ---------------- MFMA flash attention: S^T = mfma(K,Q), O^T = mfma(V^T, P^T) ----------------
// grid (L/64, H, B), 256 thr = 4 waves, wave w owns 16 q-rows.
__global__ __launch_bounds__(256) void attn_mfma(const u16* __restrict__ qb, const u16* __restrict__ kb,
                                                 const u16* __restrict__ vt, u16* __restrict__ ob) {
    int bx = blockIdx.x, h = blockIdx.y, b = blockIdx.z;
    int tid = threadIdx.x, lane = tid & 63, w = tid >> 6;
    int l15 = lane & 15, g = lane >> 4;
    __shared__ u16 Ks[32*64];       // [key][dh], 128B rows, XOR swizzled
    __shared__ u16 Vs[64*40];       // [dh][key], 80B rows (32 keys + 8 pad)
    __shared__ u16 Ps[4][16*40];    // per-wave P [q][key], 80B rows
    int qbase = bx*64;
    int qrow = qbase + w*16 + l15;

    // Q B-fragments, held in registers whole kernel (2 ksubs over DH=64)
    const u16* qptr = qb + ((size_t)(b*Ldim + qrow))*D_MODEL + h*DH + g*8;
    bf16x8 qf[2];
    qf[0] = *(const bf16x8*)(qptr);
    qf[1] = *(const bf16x8*)(qptr + 32);

    f32x4 o_acc[4] = {};
    float m_run = -INFINITY, l_run = 0.f;
    int ntiles = bx*2 + 2;

    for (int kt = 0; kt < ntiles; ++kt) {
        __syncthreads();
        {   // stage K tile: 32 keys x 64 dh
            int row = tid >> 3, slot = tid & 7;
            bf16x8 v = *(const bf16x8*)(kb + ((size_t)(b*Ldim + kt*32 + row))*D_MODEL + h*DH + slot*8);
            *(bf16x8*)((char*)Ks + row*128 + ((slot ^ (row&7)) << 4)) = v;
        }
        {   // stage V^T tile: 64 dh x 32 keys (from pre-transposed global V^T)
            int row = tid >> 2, slot = tid & 3;
            bf16x8 v = *(const bf16x8*)(vt + ((size_t)(b*D_MODEL + h*DH + row))*Ldim + kt*32 + slot*8);
            *(bf16x8*)((char*)Vs + row*80 + slot*16) = v;
        }
        __syncthreads();

        // S^T (32 keys x 16 q) = K . Q^T
        f32x4 sf[2];
        #pragma unroll
        for (int f = 0; f < 2; ++f) {
            f32x4 a = {0.f, 0.f, 0.f, 0.f};
            #pragma unroll
            for (int ks = 0; ks < 2; ++ks) {
                int row = f*16 + l15;
                bf16x8 kf = *(const bf16x8*)((const char*)Ks + row*128 + (((ks*4+g) ^ (row&7)) << 4));
                a = __builtin_amdgcn_mfma_f32_16x16x32_bf16(kf, qf[ks], a, 0, 0, 0);
            }
            sf[f] = a;
        }

        // scale + causal mask + online softmax (reduce over key axis = lanes xor 16,32 + regs)
        float pmax = -INFINITY;
        #pragma unroll
        for (int f = 0; f < 2; ++f)
            #pragma unroll
            for (int r = 0; r < 4; ++r) {
                int key = kt*32 + f*16 + g*4 + r;
                float sv = (key <= qrow) ? sf[f][r]*0.125f : -INFINITY;
                sf[f][r] = sv;
                pmax = fmaxf(pmax, sv);
            }
        pmax = fmaxf(pmax, __shfl_xor(pmax, 16));
        pmax = fmaxf(pmax, __shfl_xor(pmax, 32));
        float mnew = fmaxf(m_run, pmax);
        float corr = __expf(m_run - mnew);

        float ps = 0.f;
        #pragma unroll
        for (int f = 0; f < 2; ++f) {
            float p0 = __expf(sf[f][0] - mnew), p1 = __expf(sf[f][1] - mnew);
            float p2 = __expf(sf[f][2] - mnew), p3 = __expf(sf[f][3] - mnew);
            ps += p0 + p1 + p2 + p3;
            u16x4 pk; pk.x = f2b(p0); pk.y = f2b(p1); pk.z = f2b(p2); pk.w = f2b(p3);
            *(u16x4*)((char*)&Ps[w][0] + l15*80 + f*32 + g*8) = pk;
        }
        ps += __shfl_xor(ps, 16);
        ps += __shfl_xor(ps, 32);
        l_run = l_run * corr + ps;
        m_run = mnew;
        #pragma unroll
        for (int t = 0; t < 4; ++t) o_acc[t] *= corr;

        // PV: O^T[dh][q] += V^T . P^T   (same-wave LDS RAW: compiler inserts lgkmcnt)
        bf16x8 pf = *(const bf16x8*)((const char*)&Ps[w][0] + l15*80 + g*16);
        #pragma unroll
        for (int t = 0; t < 4; ++t) {
            int row = t*16 + l15;
            bf16x8 vf = *(const bf16x8*)((const char*)Vs + row*80 + g*16);
            o_acc[t] = __builtin_amdgcn_mfma_f32_16x16x32_bf16(vf, pf, o_acc[t], 0, 0, 0);
        }
    }

    float invl = 1.f / l_run;
    #pragma unroll
    for (int t = 0; t < 4; ++t) {
        u16x4 o4;
        o4.x = f2b(o_acc[t][0]*invl); o4.y = f2b(o_acc[t][1]*invl);
        o4.z = f2b(o_acc[t][2]*invl); o4.w = f2b(o_acc[t][3]*invl);
        *(u16x4*)(ob + ((size_t)(b*Ldim + qrow))*D_MODEL + h*DH + t*16 + g*4) = o4;
    }
}

extern "C" void kernel_launch(void* const* d_in, const int* in_sizes, int n_in,
                              void* d_out, int out_size, void* d_ws, size_t ws_size,
                              hipStream_t stream) {
    const float* x_dec   = (const float*)d_in[0];
    const float* x_mark  = (const float*)d_in[1];
    const float* token_w = (const float*)d_in[2];
    const float* temp_w  = (const float*)d_in[3];
    const float* in_proj_w = (const float*)d_in[4];
    const float* conv_w  = (const float*)d_in[5];
    const float* conv_b  = (const float*)d_in[6];
    const float* x_proj_w = (const float*)d_in[7];
    const float* dt_w    = (const float*)d_in[8];
    const float* dt_b    = (const float*)d_in[9];
    const float* A_log   = (const float*)d_in[10];
    const float* D_skip  = (const float*)d_in[11];
    const float* out_w_m = (const float*)d_in[12];
    const float* wq = (const float*)d_in[13];
    const float* bq = (const float*)d_in[14];
    const float* wk = (const float*)d_in[15];
    const float* bk = (const float*)d_in[16];
    const float* wv = (const float*)d_in[17];
    const float* bv = (const float*)d_in[18];
    const float* wo = (const float*)d_in[19];
    const float* bo = (const float*)d_in[20];
    const float* ln1_g = (const float*)d_in[21];
    const float* ln1_b = (const float*)d_in[22];
    const float* ln2_g = (const float*)d_in[23];
    const float* ln2_b = (const float*)d_in[24];
    const float* proj_w = (const float*)d_in[25];
    const float* proj_b = (const float*)d_in[26];

    if (ws_size < 164*MB) return;

    char* wsb = (char*)d_ws;
    float* x     = (float*)(wsb + 0);          // 16MB
    u16*   xbf   = (u16*)(wsb + 16*MB);        // 8MB
    u16*   xzb   = (u16*)(wsb + 24*MB);        // 32MB (aliased by q/k/vt/o after scan)
    u16*   qbf   = (u16*)(wsb + 24*MB);        // 8MB
    u16*   kbf   = (u16*)(wsb + 32*MB);        // 8MB
    u16*   vtb   = (u16*)(wsb + 40*MB);        // 8MB
    u16*   obf   = (u16*)(wsb + 48*MB);        // 8MB
    float* uc    = (float*)(wsb + 56*MB);      // 32MB
    u16*   ucb   = (u16*)(wsb + 88*MB);        // 16MB
    float* dbc   = (float*)(wsb + 104*MB);     // 2MB
    float* delta = (float*)(wsb + 106*MB);     // 32MB
    float* tmp   = delta;                      // alias: delta dead when tmp used
    u16*   ysb   = (u16*)(wsb + 138*MB);       // 16MB
    u16*   iprT  = (u16*)(wsb + 154*MB);       // 4MB  (2 layers x 2048x512)
    u16*   outT  = (u16*)(wsb + 158*MB);       // 2MB  (2 x 512x1024)
    u16*   qT    = (u16*)(wsb + 160*MB);       // 1MB
    u16*   kT    = (u16*)(wsb + 161*MB);       // 1MB
    u16*   vT    = (u16*)(wsb + 162*MB);       // 1MB
    u16*   oT    = (u16*)(wsb + 163*MB);       // 1MB
    float* out   = (float*)d_out;

    // weight transpose+cast (per call; inputs restored by harness every launch)
    transpose_cast<<<dim3(32, 8, 2), 256, 0, stream>>>(in_proj_w, iprT, 512, 2048);
    transpose_cast<<<dim3(8, 16, 2), 256, 0, stream>>>(out_w_m, outT, 1024, 512);
    transpose_cast<<<dim3(8, 8, 2), 256, 0, stream>>>(wq, qT, 512, 512);
    transpose_cast<<<dim3(8, 8, 2), 256, 0, stream>>>(wk, kT, 512, 512);
    transpose_cast<<<dim3(8, 8, 2), 256, 0, stream>>>(wv, vT, 512, 512);
    transpose_cast<<<dim3(8, 8, 2), 256, 0, stream>>>(wo, oT, 512, 512);

    embed_kernel<<<ROWS, 256, 0, stream>>>(x_dec, x_mark, token_w, temp_w, x, xbf);

    for (int i = 0; i < 2; ++i) {
        // xz = x @ in_proj   (8192 x 2048 x 512), bf16 out
        gemm_bf16<1><<<dim3(16,64), 256, 0, stream>>>(xbf, iprT + (size_t)i*2048*512, nullptr,
                                                      xzb, 2048, 512, 2048);
        conv_silu_kernel<<<(ROWS*D_INNER)/256, 256, 0, stream>>>(xzb, conv_w + i*D_INNER*D_CONV,
                                                                 conv_b + i*D_INNER, uc, ucb);
        // dbc = uc @ x_proj   (8192 x 64 x 1024), fp32
        gemm_f32<0><<<dim3(1,64), 256, 0, stream>>>(uc, 1024, x_proj_w + i*D_INNER*64, 64,
                                                    nullptr, dbc, 64, ROWS, 64, 1024);
        // delta = softplus(dt @ dt_w + dt_b)   (8192 x 1024 x 32), fp32
        gemm_f32<1><<<dim3(8,64), 256, 0, stream>>>(dbc, 64, dt_w + i*DT_RANK*D_INNER, 1024,
                                                    dt_b + i*D_INNER, delta, 1024, ROWS, 1024, DT_RANK);
        // scan + skip + silu(z) gate -> ys bf16
        scan_kernel<<<ROWS/64, 64, 0, stream>>>(delta, uc, dbc, A_log + i*D_INNER*D_STATE,
                                                xzb, D_skip + i*D_INNER, ysb);
        // tmp = ys @ out_w   (8192 x 512 x 1024), f32 out
        gemm_bf16<0><<<dim3(4,64), 256, 0, stream>>>(ysb, outT + (size_t)i*512*1024, nullptr,
                                                     tmp, 512, 1024, 512);
        ln_kernel<<<ROWS/4, 256, 0, stream>>>(x, tmp, ln1_g + i*512, ln1_b + i*512, xbf);
        // q,k bf16; v transposed bf16
        gemm_bf16<1><<<dim3(4,64), 256, 0, stream>>>(xbf, qT + (size_t)i*512*512, bq + i*512,
                                                     qbf, 512, 512, 512);
        gemm_bf16<1><<<dim3(4,64), 256, 0, stream>>>(xbf, kT + (size_t)i*512*512, bk + i*512,
                                                     kbf, 512, 512, 512);
        gemm_bf16<2><<<dim3(4,64), 256, 0, stream>>>(xbf, vT + (size_t)i*512*512, bv + i*512,
                                                     vtb, 512, 512, 512);
        attn_mfma<<<dim3(Ldim/64, N_HEADS, Bdim), 256, 0, stream>>>(qbf, kbf, vtb, obf);
        // tmp = o @ wo + bo   (8192 x 512 x 512), f32 out
        gemm_bf16<0><<<dim3(4,64), 256, 0, stream>>>(obf, oT + (size_t)i*512*512, bo + i*512,
                                                     tmp, 512, 512, 512);
        ln_kernel<<<ROWS/4, 256, 0, stream>>>(x, tmp, ln2_g + i*512, ln2_b + i*512, xbf);
    }
    // out = x @ proj_w + proj_b   (8192 x 7 x 512), fp32
    gemm_f32<0><<<dim3(1,64), 256, 0, stream>>>(x, 512, proj_w, 7, proj_b, out, 7, ROWS, 7, 512);
}

// Round 4
// 1356.769 us; speedup vs baseline: 4.5450x; 1.8850x over previous
//
#include <hip/hip_runtime.h>
#include <math.h>

#define Bdim 8
#define Ldim 1024
#define DEC_IN 7
#define D_MODEL 512
#define MARK 4
#define D_INNER 1024
#define D_STATE 16
#define D_CONV 4
#define DT_RANK 32
#define N_HEADS 8
#define DH 64
#define ROWS (Bdim*Ldim)   // 8192
#define MB (1ull<<20)
#define NCHUNK 16
#define CLEN 64            // Ldim / NCHUNK

typedef unsigned short u16;
typedef unsigned int u32;
typedef __attribute__((ext_vector_type(8))) short bf16x8;
typedef __attribute__((ext_vector_type(4))) float f32x4;
typedef __attribute__((ext_vector_type(4))) unsigned short u16x4;

__device__ inline float b2f(u16 u) {
    union { u32 i; float f; } c; c.i = ((u32)u) << 16; return c.f;
}
__device__ inline u16 f2b(float f) {
    union { float f; u32 u; } c; c.f = f;
    u32 u = c.u;
    u32 r = (u + 0x7fffu + ((u >> 16) & 1u)) >> 16;
    return (u16)r;
}

// ---------------- embed: token circular conv3 + pos embed + mark proj (dual f32/bf16 out) ----------------
__global__ void embed_kernel(const float* __restrict__ xd, const float* __restrict__ xmark,
                             const float* __restrict__ token_w, const float* __restrict__ temp_w,
                             float* __restrict__ x, u16* __restrict__ xbf) {
    int bt = blockIdx.x;            // 0..8191
    int b = bt >> 10, t = bt & 1023;
    __shared__ float xr[3][DEC_IN];
    __shared__ float mk[MARK];
    if (threadIdx.x < 3*DEC_IN) {
        int k = threadIdx.x / DEC_IN, c = threadIdx.x % DEC_IN;
        int tt = (t + k - 1 + Ldim) % Ldim;
        xr[k][c] = xd[((size_t)b*Ldim + tt)*DEC_IN + c];
    }
    if (threadIdx.x < MARK) mk[threadIdx.x] = xmark[((size_t)b*Ldim + t)*MARK + threadIdx.x];
    __syncthreads();
    for (int dd = threadIdx.x; dd < D_MODEL; dd += 256) {
        float acc = 0.f;
        #pragma unroll
        for (int k = 0; k < 3; ++k)
            #pragma unroll
            for (int c = 0; c < DEC_IN; ++c)
                acc += xr[k][c] * token_w[(k*DEC_IN + c)*D_MODEL + dd];
        int i2 = dd & ~1;
        float freq = expf(-(float)i2 * (logf(10000.f) / (float)D_MODEL));
        float ang = (float)t * freq;
        acc += (dd & 1) ? cosf(ang) : sinf(ang);
        #pragma unroll
        for (int m = 0; m < MARK; ++m) acc += mk[m] * temp_w[m*D_MODEL + dd];
        x[(size_t)bt*D_MODEL + dd] = acc;
        xbf[(size_t)bt*D_MODEL + dd] = f2b(acc);
    }
}

// ---------------- weight transpose + cast: W[K][N] f32 -> Wt[N][K] bf16 ----------------
__global__ __launch_bounds__(256) void transpose_cast(const float* __restrict__ W, u16* __restrict__ Wt,
                                                      int K, int N) {
    const float* Wz = W + (size_t)blockIdx.z * K * N;
    u16* Wtz = Wt + (size_t)blockIdx.z * K * N;
    __shared__ u16 tile[64][72];
    int k0 = blockIdx.y*64, n0 = blockIdx.x*64;
    int tid = threadIdx.x;
    #pragma unroll
    for (int it = 0; it < 16; ++it) {
        int idx = it*256 + tid; int kr = idx>>6, nc = idx&63;
        tile[kr][nc] = f2b(Wz[(size_t)(k0+kr)*N + n0 + nc]);
    }
    __syncthreads();
    #pragma unroll
    for (int it = 0; it < 2; ++it) {
        int idx = it*256 + tid; int nr = idx>>3, slot = idx&7;
        bf16x8 v;
        #pragma unroll
        for (int j = 0; j < 8; ++j) ((u16*)&v)[j] = tile[slot*8+j][nr];
        *(bf16x8*)(Wtz + (size_t)(n0+nr)*K + k0 + slot*8) = v;
    }
}

// ---------------- bf16 MFMA GEMM: C = A@Wt^T (+bias). A[M][K] bf16, Wt[N][K] bf16 ----------------
// OUTMODE: 0 = f32 out, 1 = bf16 out, 2 = bf16 transposed out (vt[b][col][t], for V)
template<int OUTMODE>
__global__ __launch_bounds__(256) void gemm_bf16(const u16* __restrict__ A, const u16* __restrict__ Bt,
                                                 const float* __restrict__ bias, void* __restrict__ Cp,
                                                 int N, int K, int ldc) {
    __shared__ u16 As[128*64];
    __shared__ u16 Bs[128*64];
    int tid = threadIdx.x;
    int bm = blockIdx.y*128, bn = blockIdx.x*128;
    int lane = tid & 63, wv = tid >> 6;
    int rm = (wv & 1)*64, cn = (wv >> 1)*64;
    int l15 = lane & 15, g = lane >> 4;

    f32x4 acc[4][4] = {};

    for (int k0 = 0; k0 < K; k0 += 64) {
        __syncthreads();
        #pragma unroll
        for (int it = 0; it < 4; ++it) {
            int idx = it*256 + tid;
            int row = idx >> 3, slot = idx & 7;
            bf16x8 av = *(const bf16x8*)(A + (size_t)(bm+row)*K + k0 + slot*8);
            *(bf16x8*)((char*)As + row*128 + ((slot ^ (row&7)) << 4)) = av;
            bf16x8 bv = *(const bf16x8*)(Bt + (size_t)(bn+row)*K + k0 + slot*8);
            *(bf16x8*)((char*)Bs + row*128 + ((slot ^ (row&7)) << 4)) = bv;
        }
        __syncthreads();
        #pragma unroll
        for (int ks = 0; ks < 2; ++ks) {
            bf16x8 af[4], bfr[4];
            #pragma unroll
            for (int m = 0; m < 4; ++m) {
                int row = rm + m*16 + l15;
                af[m] = *(const bf16x8*)((const char*)As + row*128 + (((ks*4+g) ^ (row&7)) << 4));
                int col = cn + m*16 + l15;
                bfr[m] = *(const bf16x8*)((const char*)Bs + col*128 + (((ks*4+g) ^ (col&7)) << 4));
            }
            #pragma unroll
            for (int m = 0; m < 4; ++m)
                #pragma unroll
                for (int n = 0; n < 4; ++n)
                    acc[m][n] = __builtin_amdgcn_mfma_f32_16x16x32_bf16(af[m], bfr[n], acc[m][n], 0, 0, 0);
        }
    }

    float bv4[4];
    #pragma unroll
    for (int n = 0; n < 4; ++n) bv4[n] = bias ? bias[bn + cn + n*16 + l15] : 0.f;

    #pragma unroll
    for (int m = 0; m < 4; ++m) {
        #pragma unroll
        for (int n = 0; n < 4; ++n) {
            int col = bn + cn + n*16 + l15;
            #pragma unroll
            for (int r = 0; r < 4; ++r) {
                int row = bm + rm + m*16 + g*4 + r;
                float v = acc[m][n][r] + bv4[n];
                if (OUTMODE == 0) {
                    ((float*)Cp)[(size_t)row*ldc + col] = v;
                } else if (OUTMODE == 1) {
                    ((u16*)Cp)[(size_t)row*ldc + col] = f2b(v);
                } else {
                    int b = row >> 10, t = row & 1023;
                    ((u16*)Cp)[((size_t)(b*D_MODEL) + col)*Ldim + t] = f2b(v);
                }
            }
        }
    }
}

// ---------------- generic fp32 GEMM (small shapes: x_proj, dt, final proj) ----------------
template<int ACT>  // 0=none, 1=softplus
__global__ __launch_bounds__(256) void gemm_f32(const float* __restrict__ A, int lda,
                                                const float* __restrict__ W, int ldw,
                                                const float* __restrict__ bias,
                                                float* __restrict__ C, int ldc,
                                                int M, int N, int K) {
    __shared__ float As[8][128];
    __shared__ float Bs[8][128];
    int bm = blockIdx.y * 128;
    int bn = blockIdx.x * 128;
    int tx = threadIdx.x & 15, ty = threadIdx.x >> 4;
    bool wAligned = ((ldw & 3) == 0);

    float acc[8][8];
    #pragma unroll
    for (int i = 0; i < 8; ++i)
        #pragma unroll
        for (int j = 0; j < 8; ++j) acc[i][j] = 0.f;

    int arow = threadIdx.x >> 1;
    int ak4  = (threadIdx.x & 1) * 4;
    int bkrow = threadIdx.x >> 5;
    int bcol  = (threadIdx.x & 31) * 4;

    for (int k0 = 0; k0 < K; k0 += 8) {
        __syncthreads();
        {
            float4 av = *(const float4*)(A + (size_t)(bm + arow)*lda + k0 + ak4);
            As[ak4+0][arow] = av.x;
            As[ak4+1][arow] = av.y;
            As[ak4+2][arow] = av.z;
            As[ak4+3][arow] = av.w;
        }
        {
            const float* wp = W + (size_t)(k0 + bkrow)*ldw + bn + bcol;
            float4 bv;
            if (wAligned && (bn + bcol + 3 < N)) {
                bv = *(const float4*)wp;
            } else {
                bv.x = (bn+bcol+0 < N) ? wp[0] : 0.f;
                bv.y = (bn+bcol+1 < N) ? wp[1] : 0.f;
                bv.z = (bn+bcol+2 < N) ? wp[2] : 0.f;
                bv.w = (bn+bcol+3 < N) ? wp[3] : 0.f;
            }
            *(float4*)&Bs[bkrow][bcol] = bv;
        }
        __syncthreads();
        #pragma unroll
        for (int k = 0; k < 8; ++k) {
            float4 a0 = *(const float4*)&As[k][ty*4];
            float4 a1 = *(const float4*)&As[k][64 + ty*4];
            float4 b0 = *(const float4*)&Bs[k][tx*4];
            float4 b1 = *(const float4*)&Bs[k][64 + tx*4];
            float a[8] = {a0.x,a0.y,a0.z,a0.w,a1.x,a1.y,a1.z,a1.w};
            float bb[8] = {b0.x,b0.y,b0.z,b0.w,b1.x,b1.y,b1.z,b1.w};
            #pragma unroll
            for (int i = 0; i < 8; ++i)
                #pragma unroll
                for (int j = 0; j < 8; ++j)
                    acc[i][j] = fmaf(a[i], bb[j], acc[i][j]);
        }
    }
    #pragma unroll
    for (int i = 0; i < 8; ++i) {
        int r = bm + ((i < 4) ? (ty*4 + i) : (64 + ty*4 + i - 4));
        if (r >= M) continue;
        #pragma unroll
        for (int j = 0; j < 8; ++j) {
            int c = bn + ((j < 4) ? (tx*4 + j) : (64 + tx*4 + j - 4));
            if (c >= N) continue;
            float v = acc[i][j];
            if (bias) v += bias[c];
            if (ACT == 1) v = (v > 20.f) ? v : log1pf(expf(v));
            C[(size_t)r*ldc + c] = v;
        }
    }
}

// ---------------- causal conv1d (k=4) + SiLU, bf16 in, f32 out ----------------
__global__ void conv_silu_kernel(const u16* __restrict__ xz, const float* __restrict__ conv_w,
                                 const float* __restrict__ conv_b, float* __restrict__ uc) {
    int idx = blockIdx.x * 256 + threadIdx.x;    // over B*L*D_INNER
    if (idx >= Bdim*Ldim*D_INNER) return;
    int d = idx & 1023;
    int bt = idx >> 10;
    int t = bt & 1023, b = bt >> 10;
    float acc = conv_b[d];
    #pragma unroll
    for (int k = 0; k < 4; ++k) {
        int tt = t + k - 3;
        if (tt >= 0) acc = fmaf(b2f(xz[((size_t)(b*Ldim + tt))*2048 + d]), conv_w[d*4 + k], acc);
    }
    uc[idx] = acc / (1.f + expf(-acc));
}

// ---------------- chunked selective scan, pass 1: per-chunk local scan from h=0 ----------------
// grid (32, NCHUNK), 256 thr. Emits h_end and aprod (=prod of e over chunk) per (chunk,b,d,s).
__global__ __launch_bounds__(256) void scan_part1(const float* __restrict__ delta,
                                                  const float* __restrict__ uc,
                                                  const float* __restrict__ dbc,
                                                  const float* __restrict__ A_log,
                                                  float* __restrict__ hend,
                                                  float* __restrict__ aprod) {
    int c = blockIdx.y;
    int bd = blockIdx.x*256 + threadIdx.x;   // 0..8191
    int d = bd & 1023, b = bd >> 10;
    float A[D_STATE], h[D_STATE], ap[D_STATE];
    #pragma unroll
    for (int s = 0; s < D_STATE; ++s) { A[s] = -__expf(A_log[d*D_STATE + s]); h[s] = 0.f; ap[s] = 1.f; }
    const float* dptr = delta + (size_t)b*Ldim*D_INNER + d;
    const float* uptr = uc    + (size_t)b*Ldim*D_INNER + d;
    const float* bc   = dbc   + (size_t)b*Ldim*64;
    for (int tt = 0; tt < CLEN; ++tt) {
        int t = c*CLEN + tt;
        float dl = dptr[(size_t)t*D_INNER];
        float ut = uptr[(size_t)t*D_INNER];
        float du = dl * ut;
        float4 b0 = *(const float4*)(bc + t*64 + 32);
        float4 b1 = *(const float4*)(bc + t*64 + 36);
        float4 b2 = *(const float4*)(bc + t*64 + 40);
        float4 b3 = *(const float4*)(bc + t*64 + 44);
        float Bv[16] = {b0.x,b0.y,b0.z,b0.w, b1.x,b1.y,b1.z,b1.w,
                        b2.x,b2.y,b2.z,b2.w, b3.x,b3.y,b3.z,b3.w};
        #pragma unroll
        for (int s = 0; s < D_STATE; ++s) {
            float e = __expf(dl * A[s]);
            h[s] = fmaf(e, h[s], du * Bv[s]);
            ap[s] *= e;
        }
    }
    size_t o = ((size_t)c*ROWS + bd)*D_STATE;
    #pragma unroll
    for (int q = 0; q < 4; ++q) {
        *(float4*)(hend  + o + q*4) = make_float4(h[q*4],  h[q*4+1],  h[q*4+2],  h[q*4+3]);
        *(float4*)(aprod + o + q*4) = make_float4(ap[q*4], ap[q*4+1], ap[q*4+2], ap[q*4+3]);
    }
}

// ---------------- pass 2: combine chunk states; hend[c] := incoming state h_in[c] ----------------
__global__ __launch_bounds__(256) void scan_part2(float* __restrict__ hend,
                                                  const float* __restrict__ aprod) {
    int idx = blockIdx.x*256 + threadIdx.x;  // 0..131071  (= ROWS*D_STATE)
    float hin = 0.f;
    #pragma unroll
    for (int c = 0; c < NCHUNK; ++c) {
        size_t o = (size_t)c*ROWS*D_STATE + idx;
        float he = hend[o], ap = aprod[o];
        hend[o] = hin;
        hin = fmaf(ap, hin, he);
    }
}

// ---------------- pass 3: replay chunk from h_in, fused skip + silu(z) gate, bf16 out ----------------
__global__ __launch_bounds__(256) void scan_part3(const float* __restrict__ delta,
                                                  const float* __restrict__ uc,
                                                  const float* __restrict__ dbc,
                                                  const float* __restrict__ A_log,
                                                  const float* __restrict__ hend,
                                                  const u16* __restrict__ xz,
                                                  const float* __restrict__ Dskip,
                                                  u16* __restrict__ ysb) {
    int c = blockIdx.y;
    int bd = blockIdx.x*256 + threadIdx.x;
    int d = bd & 1023, b = bd >> 10;
    float A[D_STATE], h[D_STATE];
    size_t o = ((size_t)c*ROWS + bd)*D_STATE;
    #pragma unroll
    for (int s = 0; s < D_STATE; ++s) {
        A[s] = -__expf(A_log[d*D_STATE + s]);
        h[s] = hend[o + s];
    }
    float Dk = Dskip[d];
    const float* dptr = delta + (size_t)b*Ldim*D_INNER + d;
    const float* uptr = uc    + (size_t)b*Ldim*D_INNER + d;
    const float* bc   = dbc   + (size_t)b*Ldim*64;
    const u16*   zp   = xz    + (size_t)b*Ldim*2048 + 1024 + d;
    u16* yp = ysb + (size_t)b*Ldim*D_INNER + d;
    for (int tt = 0; tt < CLEN; ++tt) {
        int t = c*CLEN + tt;
        float dl = dptr[(size_t)t*D_INNER];
        float ut = uptr[(size_t)t*D_INNER];
        float du = dl * ut;
        float4 b0 = *(const float4*)(bc + t*64 + 32);
        float4 b1 = *(const float4*)(bc + t*64 + 36);
        float4 b2 = *(const float4*)(bc + t*64 + 40);
        float4 b3 = *(const float4*)(bc + t*64 + 44);
        float4 c0 = *(const float4*)(bc + t*64 + 48);
        float4 c1 = *(const float4*)(bc + t*64 + 52);
        float4 c2 = *(const float4*)(bc + t*64 + 56);
        float4 c3 = *(const float4*)(bc + t*64 + 60);
        float Bv[16] = {b0.x,b0.y,b0.z,b0.w, b1.x,b1.y,b1.z,b1.w,
                        b2.x,b2.y,b2.z,b2.w, b3.x,b3.y,b3.z,b3.w};
        float Cv[16] = {c0.x,c0.y,c0.z,c0.w, c1.x,c1.y,c1.z,c1.w,
                        c2.x,c2.y,c2.z,c2.w, c3.x,c3.y,c3.z,c3.w};
        float y = 0.f;
        #pragma unroll
        for (int s = 0; s < D_STATE; ++s) {
            float e = __expf(dl * A[s]);
            h[s] = fmaf(e, h[s], du * Bv[s]);
            y = fmaf(h[s], Cv[s], y);
        }
        float z = b2f(zp[(size_t)t*2048]);
        float yy = fmaf(ut, Dk, y);
        yp[(size_t)t*D_INNER] = f2b(yy * (z / (1.f + __expf(-z))));
    }
}

// ---------------- fused residual + LayerNorm, dual f32/bf16 out ----------------
__global__ __launch_bounds__(256) void ln_kernel(float* __restrict__ x, const float* __restrict__ t,
                                                 const float* __restrict__ g, const float* __restrict__ bta,
                                                 u16* __restrict__ xbf) {
    int row = blockIdx.x * 4 + (threadIdx.x >> 6);
    int lane = threadIdx.x & 63;
    const float* xr = x + (size_t)row*D_MODEL;
    const float* tr = t + (size_t)row*D_MODEL;
    float v[8];
    float sum = 0.f;
    #pragma unroll
    for (int j = 0; j < 8; ++j) { v[j] = xr[lane + j*64] + tr[lane + j*64]; sum += v[j]; }
    #pragma unroll
    for (int off = 32; off; off >>= 1) sum += __shfl_xor(sum, off);
    float mu = sum * (1.f/512.f);
    float vs = 0.f;
    #pragma unroll
    for (int j = 0; j < 8; ++j) { float dm = v[j] - mu; vs += dm*dm; }
    #pragma unroll
    for (int off = 32; off; off >>= 1) vs += __shfl_xor(vs, off);
    float inv = rsqrtf(vs * (1.f/512.f) + 1e-5f);
    #pragma unroll
    for (int j = 0; j < 8; ++j) {
        int c = lane + j*64;
        float o = (v[j] - mu) * inv * g[c] + bta[c];
        x[(size_t)row*D_MODEL + c] = o;
        xbf[(size_t)row*D_MODEL + c] = f2b(o);
    }
}

// ---------------- MFMA flash attention: S^T = mfma(K,Q), O^T = mfma(V^T, P^T) ----------------
__global__ __launch_bounds__(256) void attn_mfma(const u16* __restrict__ qb, const u16* __restrict__ kb,
                                                 const u16* __restrict__ vt, u16* __restrict__ ob) {
    int bx = blockIdx.x, h = blockIdx.y, b = blockIdx.z;
    int tid = threadIdx.x, lane = tid & 63, w = tid >> 6;
    int l15 = lane & 15, g = lane >> 4;
    __shared__ u16 Ks[32*64];       // [key][dh], 128B rows, XOR swizzled
    __shared__ u16 Vs[64*40];       // [dh][key], 80B rows (32 keys + 8 pad)
    __shared__ u16 Ps[4][16*40];    // per-wave P [q][key], 80B rows
    int qbase = bx*64;
    int qrow = qbase + w*16 + l15;

    const u16* qptr = qb + ((size_t)(b*Ldim + qrow))*D_MODEL + h*DH + g*8;
    bf16x8 qf[2];
    qf[0] = *(const bf16x8*)(qptr);
    qf[1] = *(const bf16x8*)(qptr + 32);

    f32x4 o_acc[4] = {};
    float m_run = -INFINITY, l_run = 0.f;
    int ntiles = bx*2 + 2;

    for (int kt = 0; kt < ntiles; ++kt) {
        __syncthreads();
        {   // stage K tile: 32 keys x 64 dh
            int row = tid >> 3, slot = tid & 7;
            bf16x8 v = *(const bf16x8*)(kb + ((size_t)(b*Ldim + kt*32 + row))*D_MODEL + h*DH + slot*8);
            *(bf16x8*)((char*)Ks + row*128 + ((slot ^ (row&7)) << 4)) = v;
        }
        {   // stage V^T tile: 64 dh x 32 keys
            int row = tid >> 2, slot = tid & 3;
            bf16x8 v = *(const bf16x8*)(vt + ((size_t)(b*D_MODEL + h*DH + row))*Ldim + kt*32 + slot*8);
            *(bf16x8*)((char*)Vs + row*80 + slot*16) = v;
        }
        __syncthreads();

        // S^T (32 keys x 16 q) = K . Q^T
        f32x4 sf[2];
        #pragma unroll
        for (int f = 0; f < 2; ++f) {
            f32x4 a = {0.f, 0.f, 0.f, 0.f};
            #pragma unroll
            for (int ks = 0; ks < 2; ++ks) {
                int row = f*16 + l15;
                bf16x8 kf = *(const bf16x8*)((const char*)Ks + row*128 + (((ks*4+g) ^ (row&7)) << 4));
                a = __builtin_amdgcn_mfma_f32_16x16x32_bf16(kf, qf[ks], a, 0, 0, 0);
            }
            sf[f] = a;
        }

        float pmax = -INFINITY;
        #pragma unroll
        for (int f = 0; f < 2; ++f)
            #pragma unroll
            for (int r = 0; r < 4; ++r) {
                int key = kt*32 + f*16 + g*4 + r;
                float sv = (key <= qrow) ? sf[f][r]*0.125f : -INFINITY;
                sf[f][r] = sv;
                pmax = fmaxf(pmax, sv);
            }
        pmax = fmaxf(pmax, __shfl_xor(pmax, 16));
        pmax = fmaxf(pmax, __shfl_xor(pmax, 32));
        float mnew = fmaxf(m_run, pmax);
        float corr = __expf(m_run - mnew);

        float ps = 0.f;
        #pragma unroll
        for (int f = 0; f < 2; ++f) {
            float p0 = __expf(sf[f][0] - mnew), p1 = __expf(sf[f][1] - mnew);
            float p2 = __expf(sf[f][2] - mnew), p3 = __expf(sf[f][3] - mnew);
            ps += p0 + p1 + p2 + p3;
            u16x4 pk; pk.x = f2b(p0); pk.y = f2b(p1); pk.z = f2b(p2); pk.w = f2b(p3);
            *(u16x4*)((char*)&Ps[w][0] + l15*80 + f*32 + g*8) = pk;
        }
        ps += __shfl_xor(ps, 16);
        ps += __shfl_xor(ps, 32);
        l_run = l_run * corr + ps;
        m_run = mnew;
        #pragma unroll
        for (int t = 0; t < 4; ++t) o_acc[t] *= corr;

        bf16x8 pf = *(const bf16x8*)((const char*)&Ps[w][0] + l15*80 + g*16);
        #pragma unroll
        for (int t = 0; t < 4; ++t) {
            int row = t*16 + l15;
            bf16x8 vf = *(const bf16x8*)((const char*)Vs + row*80 + g*16);
            o_acc[t] = __builtin_amdgcn_mfma_f32_16x16x32_bf16(vf, pf, o_acc[t], 0, 0, 0);
        }
    }

    float invl = 1.f / l_run;
    #pragma unroll
    for (int t = 0; t < 4; ++t) {
        u16x4 o4;
        o4.x = f2b(o_acc[t][0]*invl); o4.y = f2b(o_acc[t][1]*invl);
        o4.z = f2b(o_acc[t][2]*invl); o4.w = f2b(o_acc[t][3]*invl);
        *(u16x4*)(ob + ((size_t)(b*Ldim + qrow))*D_MODEL + h*DH + t*16 + g*4) = o4;
    }
}

extern "C" void kernel_launch(void* const* d_in, const int* in_sizes, int n_in,
                              void* d_out, int out_size, void* d_ws, size_t ws_size,
                              hipStream_t stream) {
    const float* x_dec   = (const float*)d_in[0];
    const float* x_mark  = (const float*)d_in[1];
    const float* token_w = (const float*)d_in[2];
    const float* temp_w  = (const float*)d_in[3];
    const float* in_proj_w = (const float*)d_in[4];
    const float* conv_w  = (const float*)d_in[5];
    const float* conv_b  = (const float*)d_in[6];
    const float* x_proj_w = (const float*)d_in[7];
    const float* dt_w    = (const float*)d_in[8];
    const float* dt_b    = (const float*)d_in[9];
    const float* A_log   = (const float*)d_in[10];
    const float* D_skip  = (const float*)d_in[11];
    const float* out_w_m = (const float*)d_in[12];
    const float* wq = (const float*)d_in[13];
    const float* bq = (const float*)d_in[14];
    const float* wk = (const float*)d_in[15];
    const float* bk = (const float*)d_in[16];
    const float* wv = (const float*)d_in[17];
    const float* bv = (const float*)d_in[18];
    const float* wo = (const float*)d_in[19];
    const float* bo = (const float*)d_in[20];
    const float* ln1_g = (const float*)d_in[21];
    const float* ln1_b = (const float*)d_in[22];
    const float* ln2_g = (const float*)d_in[23];
    const float* ln2_b = (const float*)d_in[24];
    const float* proj_w = (const float*)d_in[25];
    const float* proj_b = (const float*)d_in[26];

    if (ws_size < 164*MB) return;

    char* wsb = (char*)d_ws;
    float* x     = (float*)(wsb + 0);          // 16MB
    u16*   xbf   = (u16*)(wsb + 16*MB);        // 8MB
    u16*   xzb   = (u16*)(wsb + 24*MB);        // 32MB (aliased by q/k/vt/o after scan)
    u16*   qbf   = (u16*)(wsb + 24*MB);        // 8MB
    u16*   kbf   = (u16*)(wsb + 32*MB);        // 8MB
    u16*   vtb   = (u16*)(wsb + 40*MB);        // 8MB
    u16*   obf   = (u16*)(wsb + 48*MB);        // 8MB
    float* uc    = (float*)(wsb + 56*MB);      // 32MB
    float* hend  = (float*)(wsb + 88*MB);      // 8MB  (chunk states)
    float* aprod = (float*)(wsb + 96*MB);      // 8MB
    float* dbc   = (float*)(wsb + 104*MB);     // 2MB
    float* delta = (float*)(wsb + 106*MB);     // 32MB
    float* tmp   = delta;                      // alias: delta dead when tmp used
    u16*   ysb   = (u16*)(wsb + 138*MB);       // 16MB
    u16*   iprT  = (u16*)(wsb + 154*MB);       // 4MB
    u16*   outT  = (u16*)(wsb + 158*MB);       // 2MB
    u16*   qT    = (u16*)(wsb + 160*MB);       // 1MB
    u16*   kT    = (u16*)(wsb + 161*MB);       // 1MB
    u16*   vT    = (u16*)(wsb + 162*MB);       // 1MB
    u16*   oT    = (u16*)(wsb + 163*MB);       // 1MB
    float* out   = (float*)d_out;

    transpose_cast<<<dim3(32, 8, 2), 256, 0, stream>>>(in_proj_w, iprT, 512, 2048);
    transpose_cast<<<dim3(8, 16, 2), 256, 0, stream>>>(out_w_m, outT, 1024, 512);
    transpose_cast<<<dim3(8, 8, 2), 256, 0, stream>>>(wq, qT, 512, 512);
    transpose_cast<<<dim3(8, 8, 2), 256, 0, stream>>>(wk, kT, 512, 512);
    transpose_cast<<<dim3(8, 8, 2), 256, 0, stream>>>(wv, vT, 512, 512);
    transpose_cast<<<dim3(8, 8, 2), 256, 0, stream>>>(wo, oT, 512, 512);

    embed_kernel<<<ROWS, 256, 0, stream>>>(x_dec, x_mark, token_w, temp_w, x, xbf);

    for (int i = 0; i < 2; ++i) {
        gemm_bf16<1><<<dim3(16,64), 256, 0, stream>>>(xbf, iprT + (size_t)i*2048*512, nullptr,
                                                      xzb, 2048, 512, 2048);
        conv_silu_kernel<<<(ROWS*D_INNER)/256, 256, 0, stream>>>(xzb, conv_w + i*D_INNER*D_CONV,
                                                                 conv_b + i*D_INNER, uc);
        gemm_f32<0><<<dim3(1,64), 256, 0, stream>>>(uc, 1024, x_proj_w + i*D_INNER*64, 64,
                                                    nullptr, dbc, 64, ROWS, 64, 1024);
        gemm_f32<1><<<dim3(8,64), 256, 0, stream>>>(dbc, 64, dt_w + i*DT_RANK*D_INNER, 1024,
                                                    dt_b + i*D_INNER, delta, 1024, ROWS, 1024, DT_RANK);
        // chunked scan (3 passes) + fused skip/gate
        scan_part1<<<dim3(32, NCHUNK), 256, 0, stream>>>(delta, uc, dbc, A_log + i*D_INNER*D_STATE,
                                                         hend, aprod);
        scan_part2<<<(ROWS*D_STATE)/256, 256, 0, stream>>>(hend, aprod);
        scan_part3<<<dim3(32, NCHUNK), 256, 0, stream>>>(delta, uc, dbc, A_log + i*D_INNER*D_STATE,
                                                         hend, xzb, D_skip + i*D_INNER, ysb);
        gemm_bf16<0><<<dim3(4,64), 256, 0, stream>>>(ysb, outT + (size_t)i*512*1024, nullptr,
                                                     tmp, 512, 1024, 512);
        ln_kernel<<<ROWS/4, 256, 0, stream>>>(x, tmp, ln1_g + i*512, ln1_b + i*512, xbf);
        gemm_bf16<1><<<dim3(4,64), 256, 0, stream>>>(xbf, qT + (size_t)i*512*512, bq + i*512,
                                                     qbf, 512, 512, 512);
        gemm_bf16<1><<<dim3(4,64), 256, 0, stream>>>(xbf, kT + (size_t)i*512*512, bk + i*512,
                                                     kbf, 512, 512, 512);
        gemm_bf16<2><<<dim3(4,64), 256, 0, stream>>>(xbf, vT + (size_t)i*512*512, bv + i*512,
                                                     vtb, 512, 512, 512);
        attn_mfma<<<dim3(Ldim/64, N_HEADS, Bdim), 256, 0, stream>>>(qbf, kbf, vtb, obf);
        gemm_bf16<0><<<dim3(4,64), 256, 0, stream>>>(obf, oT + (size_t)i*512*512, bo + i*512,
                                                     tmp, 512, 512, 512);
        ln_kernel<<<ROWS/4, 256, 0, stream>>>(x, tmp, ln2_g + i*512, ln2_b + i*512, xbf);
    }
    gemm_f32<0><<<dim3(1,64), 256, 0, stream>>>(x, 512, proj_w, 7, proj_b, out, 7, ROWS, 7, 512);
}

// Round 5
// 964.173 us; speedup vs baseline: 6.3956x; 1.4072x over previous
//
#include <hip/hip_runtime.h>
#include <math.h>

#define Bdim 8
#define Ldim 1024
#define DEC_IN 7
#define D_MODEL 512
#define MARK 4
#define D_INNER 1024
#define D_STATE 16
#define D_CONV 4
#define DT_RANK 32
#define N_HEADS 8
#define DH 64
#define ROWS (Bdim*Ldim)   // 8192
#define MB (1ull<<20)
#define NCHUNK 16
#define CLEN 64            // Ldim / NCHUNK

typedef unsigned short u16;
typedef unsigned int u32;
typedef __attribute__((ext_vector_type(8))) short bf16x8;
typedef __attribute__((ext_vector_type(4))) float f32x4;
typedef __attribute__((ext_vector_type(4))) unsigned short u16x4;

__device__ inline float b2f(u16 u) {
    union { u32 i; float f; } c; c.i = ((u32)u) << 16; return c.f;
}
__device__ inline u16 f2b(float f) {
    union { float f; u32 u; } c; c.f = f;
    u32 u = c.u;
    u32 r = (u + 0x7fffu + ((u >> 16) & 1u)) >> 16;
    return (u16)r;
}

// ---------------- embed: token circular conv3 + pos embed + mark proj (dual f32/bf16 out) ----------------
__global__ void embed_kernel(const float* __restrict__ xd, const float* __restrict__ xmark,
                             const float* __restrict__ token_w, const float* __restrict__ temp_w,
                             float* __restrict__ x, u16* __restrict__ xbf) {
    int bt = blockIdx.x;            // 0..8191
    int b = bt >> 10, t = bt & 1023;
    __shared__ float xr[3][DEC_IN];
    __shared__ float mk[MARK];
    if (threadIdx.x < 3*DEC_IN) {
        int k = threadIdx.x / DEC_IN, c = threadIdx.x % DEC_IN;
        int tt = (t + k - 1 + Ldim) % Ldim;
        xr[k][c] = xd[((size_t)b*Ldim + tt)*DEC_IN + c];
    }
    if (threadIdx.x < MARK) mk[threadIdx.x] = xmark[((size_t)b*Ldim + t)*MARK + threadIdx.x];
    __syncthreads();
    for (int dd = threadIdx.x; dd < D_MODEL; dd += 256) {
        float acc = 0.f;
        #pragma unroll
        for (int k = 0; k < 3; ++k)
            #pragma unroll
            for (int c = 0; c < DEC_IN; ++c)
                acc += xr[k][c] * token_w[(k*DEC_IN + c)*D_MODEL + dd];
        int i2 = dd & ~1;
        float freq = expf(-(float)i2 * (logf(10000.f) / (float)D_MODEL));
        float ang = (float)t * freq;
        acc += (dd & 1) ? cosf(ang) : sinf(ang);
        #pragma unroll
        for (int m = 0; m < MARK; ++m) acc += mk[m] * temp_w[m*D_MODEL + dd];
        x[(size_t)bt*D_MODEL + dd] = acc;
        xbf[(size_t)bt*D_MODEL + dd] = f2b(acc);
    }
}

// ---------------- weight transpose + cast: W[K][N] f32 -> Wt[N][K] bf16 (K,N multiples of 64) ----------------
__global__ __launch_bounds__(256) void transpose_cast(const float* __restrict__ W, u16* __restrict__ Wt,
                                                      int K, int N) {
    const float* Wz = W + (size_t)blockIdx.z * K * N;
    u16* Wtz = Wt + (size_t)blockIdx.z * K * N;
    __shared__ u16 tile[64][72];
    int k0 = blockIdx.y*64, n0 = blockIdx.x*64;
    int tid = threadIdx.x;
    #pragma unroll
    for (int it = 0; it < 16; ++it) {
        int idx = it*256 + tid; int kr = idx>>6, nc = idx&63;
        tile[kr][nc] = f2b(Wz[(size_t)(k0+kr)*N + n0 + nc]);
    }
    __syncthreads();
    #pragma unroll
    for (int it = 0; it < 2; ++it) {
        int idx = it*256 + tid; int nr = idx>>3, slot = idx&7;
        bf16x8 v;
        #pragma unroll
        for (int j = 0; j < 8; ++j) ((u16*)&v)[j] = tile[slot*8+j][nr];
        *(bf16x8*)(Wtz + (size_t)(n0+nr)*K + k0 + slot*8) = v;
    }
}

// ---------------- dt_w transpose: [2][32][1024] f32 -> [2][1024][32] bf16 ----------------
__global__ void dtw_transpose(const float* __restrict__ dt_w, u16* __restrict__ dtwT) {
    int idx = blockIdx.x*256 + threadIdx.x;   // 0..65535
    int z = idx >> 15, rem = idx & 32767;
    int n = rem >> 5, k = rem & 31;
    dtwT[idx] = f2b(dt_w[(size_t)z*32768 + k*1024 + n]);
}

// ---------------- bf16 MFMA GEMM: C = A@Bt^T (+bias)(+act). A[M][lda], Bt[N][ldb] bf16 ----------------
// 128x128 tile, BK=64. OUTMODE: 0=f32, 1=bf16, 2=bf16 transposed (V). ACT: 0=none, 1=softplus.
// Kpad = K rounded up to 64; staging zero-fills beyond Kreal.
template<int OUTMODE, int ACT>
__global__ __launch_bounds__(256) void gemm_bf16(const u16* __restrict__ A, int lda,
                                                 const u16* __restrict__ Bt, int ldb,
                                                 const float* __restrict__ bias, void* __restrict__ Cp,
                                                 int ldc, int N, int Kpad, int Kreal) {
    __shared__ u16 As[128*64];
    __shared__ u16 Bs[128*64];
    int tid = threadIdx.x;
    int bm = blockIdx.y*128, bn = blockIdx.x*128;
    int lane = tid & 63, wv = tid >> 6;
    int rm = (wv & 1)*64, cn = (wv >> 1)*64;
    int l15 = lane & 15, g = lane >> 4;

    f32x4 acc[4][4] = {};

    for (int k0 = 0; k0 < Kpad; k0 += 64) {
        __syncthreads();
        #pragma unroll
        for (int it = 0; it < 4; ++it) {
            int idx = it*256 + tid;
            int row = idx >> 3, slot = idx & 7;
            bf16x8 av = {0,0,0,0,0,0,0,0};
            bf16x8 bv = {0,0,0,0,0,0,0,0};
            if (k0 + slot*8 < Kreal) {
                av = *(const bf16x8*)(A + (size_t)(bm+row)*lda + k0 + slot*8);
                bv = *(const bf16x8*)(Bt + (size_t)(bn+row)*ldb + k0 + slot*8);
            }
            *(bf16x8*)((char*)As + row*128 + ((slot ^ (row&7)) << 4)) = av;
            *(bf16x8*)((char*)Bs + row*128 + ((slot ^ (row&7)) << 4)) = bv;
        }
        __syncthreads();
        #pragma unroll
        for (int ks = 0; ks < 2; ++ks) {
            bf16x8 af[4], bfr[4];
            #pragma unroll
            for (int m = 0; m < 4; ++m) {
                int row = rm + m*16 + l15;
                af[m] = *(const bf16x8*)((const char*)As + row*128 + (((ks*4+g) ^ (row&7)) << 4));
                int col = cn + m*16 + l15;
                bfr[m] = *(const bf16x8*)((const char*)Bs + col*128 + (((ks*4+g) ^ (col&7)) << 4));
            }
            #pragma unroll
            for (int m = 0; m < 4; ++m)
                #pragma unroll
                for (int n = 0; n < 4; ++n)
                    acc[m][n] = __builtin_amdgcn_mfma_f32_16x16x32_bf16(af[m], bfr[n], acc[m][n], 0, 0, 0);
        }
    }

    float bv4[4];
    #pragma unroll
    for (int n = 0; n < 4; ++n) bv4[n] = bias ? bias[bn + cn + n*16 + l15] : 0.f;

    #pragma unroll
    for (int m = 0; m < 4; ++m) {
        #pragma unroll
        for (int n = 0; n < 4; ++n) {
            int col = bn + cn + n*16 + l15;
            #pragma unroll
            for (int r = 0; r < 4; ++r) {
                int row = bm + rm + m*16 + g*4 + r;
                float v = acc[m][n][r] + bv4[n];
                if (ACT == 1) v = (v > 20.f) ? v : log1pf(__expf(v));
                if (OUTMODE == 0) {
                    ((float*)Cp)[(size_t)row*ldc + col] = v;
                } else if (OUTMODE == 1) {
                    ((u16*)Cp)[(size_t)row*ldc + col] = f2b(v);
                } else {
                    int b = row >> 10, t = row & 1023;
                    ((u16*)Cp)[((size_t)(b*D_MODEL) + col)*Ldim + t] = f2b(v);
                }
            }
        }
    }
}

// ---------------- x_proj MFMA: dbc = ucb @ xprT^T (8192x64x1024), dual out f32 dbc + bf16 dtb ----------------
__global__ __launch_bounds__(256) void xproj_kernel(const u16* __restrict__ ucb, const u16* __restrict__ xprT,
                                                    float* __restrict__ dbc, u16* __restrict__ dtb) {
    __shared__ u16 As[64*64];
    __shared__ u16 Bs[64*64];
    int tid = threadIdx.x, lane = tid & 63, wv = tid >> 6;
    int l15 = lane & 15, g = lane >> 4;
    int bm = blockIdx.x*64;
    f32x4 acc[4] = {};
    for (int k0 = 0; k0 < 1024; k0 += 64) {
        __syncthreads();
        #pragma unroll
        for (int it = 0; it < 2; ++it) {
            int idx = it*256 + tid; int row = idx >> 3, slot = idx & 7;
            bf16x8 av = *(const bf16x8*)(ucb + (size_t)(bm+row)*1024 + k0 + slot*8);
            *(bf16x8*)((char*)As + row*128 + ((slot ^ (row&7)) << 4)) = av;
            bf16x8 bv = *(const bf16x8*)(xprT + (size_t)row*1024 + k0 + slot*8);
            *(bf16x8*)((char*)Bs + row*128 + ((slot ^ (row&7)) << 4)) = bv;
        }
        __syncthreads();
        #pragma unroll
        for (int ks = 0; ks < 2; ++ks) {
            int arow = wv*16 + l15;
            bf16x8 af = *(const bf16x8*)((const char*)As + arow*128 + (((ks*4+g) ^ (arow&7)) << 4));
            #pragma unroll
            for (int n = 0; n < 4; ++n) {
                int col = n*16 + l15;
                bf16x8 bfr = *(const bf16x8*)((const char*)Bs + col*128 + (((ks*4+g) ^ (col&7)) << 4));
                acc[n] = __builtin_amdgcn_mfma_f32_16x16x32_bf16(af, bfr, acc[n], 0, 0, 0);
            }
        }
    }
    #pragma unroll
    for (int n = 0; n < 4; ++n) {
        int col = n*16 + l15;
        #pragma unroll
        for (int r = 0; r < 4; ++r) {
            int row = bm + wv*16 + g*4 + r;
            float v = acc[n][r];
            dbc[(size_t)row*64 + col] = v;
            if (col < 32) dtb[(size_t)row*32 + col] = f2b(v);
        }
    }
}

// ---------------- final proj: out = x @ proj_w + proj_b (wave per row, N=7) ----------------
__global__ __launch_bounds__(256) void proj_kernel(const float* __restrict__ x, const float* __restrict__ w,
                                                   const float* __restrict__ pb, float* __restrict__ out) {
    int row = blockIdx.x*4 + (threadIdx.x >> 6);
    int lane = threadIdx.x & 63;
    const float* xr = x + (size_t)row*D_MODEL + lane*8;
    float xv[8];
    #pragma unroll
    for (int j = 0; j < 8; ++j) xv[j] = xr[j];
    const float* wr = w + lane*56;
    float acc[7] = {0,0,0,0,0,0,0};
    #pragma unroll
    for (int j = 0; j < 8; ++j)
        #pragma unroll
        for (int c = 0; c < 7; ++c) acc[c] = fmaf(xv[j], wr[j*7 + c], acc[c]);
    #pragma unroll
    for (int c = 0; c < 7; ++c) {
        #pragma unroll
        for (int off = 32; off; off >>= 1) acc[c] += __shfl_xor(acc[c], off);
    }
    if (lane < 7) out[(size_t)row*7 + lane] = acc[lane] + pb[lane];
}

// ---------------- causal conv1d (k=4) + SiLU, bf16 in, bf16x8 vectorized out ----------------
__global__ void conv_silu_kernel(const u16* __restrict__ xz, const float* __restrict__ conv_w,
                                 const float* __restrict__ conv_b, u16* __restrict__ ucb) {
    int idx = blockIdx.x*256 + threadIdx.x;   // over ROWS*128
    int d8 = idx & 127, bt = idx >> 7;
    int t = bt & 1023, b = bt >> 10;
    int d0 = d8*8;
    float acc[8];
    #pragma unroll
    for (int j = 0; j < 8; ++j) acc[j] = conv_b[d0+j];
    #pragma unroll
    for (int k = 0; k < 4; ++k) {
        int tt = t + k - 3;
        if (tt >= 0) {
            bf16x8 v = *(const bf16x8*)(xz + ((size_t)(b*Ldim + tt))*2048 + d0);
            #pragma unroll
            for (int j = 0; j < 8; ++j)
                acc[j] = fmaf(b2f(((u16*)&v)[j]), conv_w[(d0+j)*4 + k], acc[j]);
        }
    }
    bf16x8 o;
    #pragma unroll
    for (int j = 0; j < 8; ++j) {
        float s = acc[j] / (1.f + __expf(-acc[j]));
        ((u16*)&o)[j] = f2b(s);
    }
    *(bf16x8*)(ucb + (size_t)bt*1024 + d0) = o;
}

// ---------------- chunked selective scan, pass 1 ----------------
__global__ __launch_bounds__(256) void scan_part1(const float* __restrict__ delta,
                                                  const u16* __restrict__ ucb,
                                                  const float* __restrict__ dbc,
                                                  const float* __restrict__ A_log,
                                                  float* __restrict__ hend,
                                                  float* __restrict__ aprod) {
    int c = blockIdx.y;
    int bd = blockIdx.x*256 + threadIdx.x;   // 0..8191
    int d = bd & 1023, b = bd >> 10;
    float A[D_STATE], h[D_STATE], ap[D_STATE];
    #pragma unroll
    for (int s = 0; s < D_STATE; ++s) { A[s] = -__expf(A_log[d*D_STATE + s]); h[s] = 0.f; ap[s] = 1.f; }
    const float* dptr = delta + (size_t)b*Ldim*D_INNER + d;
    const u16*   uptr = ucb   + (size_t)b*Ldim*D_INNER + d;
    const float* bc   = dbc   + (size_t)b*Ldim*64;
    for (int tt = 0; tt < CLEN; ++tt) {
        int t = c*CLEN + tt;
        float dl = dptr[(size_t)t*D_INNER];
        float ut = b2f(uptr[(size_t)t*D_INNER]);
        float du = dl * ut;
        float4 b0 = *(const float4*)(bc + t*64 + 32);
        float4 b1 = *(const float4*)(bc + t*64 + 36);
        float4 b2 = *(const float4*)(bc + t*64 + 40);
        float4 b3 = *(const float4*)(bc + t*64 + 44);
        float Bv[16] = {b0.x,b0.y,b0.z,b0.w, b1.x,b1.y,b1.z,b1.w,
                        b2.x,b2.y,b2.z,b2.w, b3.x,b3.y,b3.z,b3.w};
        #pragma unroll
        for (int s = 0; s < D_STATE; ++s) {
            float e = __expf(dl * A[s]);
            h[s] = fmaf(e, h[s], du * Bv[s]);
            ap[s] *= e;
        }
    }
    size_t o = ((size_t)c*ROWS + bd)*D_STATE;
    #pragma unroll
    for (int q = 0; q < 4; ++q) {
        *(float4*)(hend  + o + q*4) = make_float4(h[q*4],  h[q*4+1],  h[q*4+2],  h[q*4+3]);
        *(float4*)(aprod + o + q*4) = make_float4(ap[q*4], ap[q*4+1], ap[q*4+2], ap[q*4+3]);
    }
}

// ---------------- pass 2: combine chunk states ----------------
__global__ __launch_bounds__(256) void scan_part2(float* __restrict__ hend,
                                                  const float* __restrict__ aprod) {
    int idx = blockIdx.x*256 + threadIdx.x;  // 0..131071
    float hin = 0.f;
    #pragma unroll
    for (int c = 0; c < NCHUNK; ++c) {
        size_t o = (size_t)c*ROWS*D_STATE + idx;
        float he = hend[o], ap = aprod[o];
        hend[o] = hin;
        hin = fmaf(ap, hin, he);
    }
}

// ---------------- pass 3: replay from h_in, fused skip + silu(z) gate, bf16 out ----------------
__global__ __launch_bounds__(256) void scan_part3(const float* __restrict__ delta,
                                                  const u16* __restrict__ ucb,
                                                  const float* __restrict__ dbc,
                                                  const float* __restrict__ A_log,
                                                  const float* __restrict__ hend,
                                                  const u16* __restrict__ xz,
                                                  const float* __restrict__ Dskip,
                                                  u16* __restrict__ ysb) {
    int c = blockIdx.y;
    int bd = blockIdx.x*256 + threadIdx.x;
    int d = bd & 1023, b = bd >> 10;
    float A[D_STATE], h[D_STATE];
    size_t o = ((size_t)c*ROWS + bd)*D_STATE;
    #pragma unroll
    for (int s = 0; s < D_STATE; ++s) {
        A[s] = -__expf(A_log[d*D_STATE + s]);
        h[s] = hend[o + s];
    }
    float Dk = Dskip[d];
    const float* dptr = delta + (size_t)b*Ldim*D_INNER + d;
    const u16*   uptr = ucb   + (size_t)b*Ldim*D_INNER + d;
    const float* bc   = dbc   + (size_t)b*Ldim*64;
    const u16*   zp   = xz    + (size_t)b*Ldim*2048 + 1024 + d;
    u16* yp = ysb + (size_t)b*Ldim*D_INNER + d;
    for (int tt = 0; tt < CLEN; ++tt) {
        int t = c*CLEN + tt;
        float dl = dptr[(size_t)t*D_INNER];
        float ut = b2f(uptr[(size_t)t*D_INNER]);
        float du = dl * ut;
        float4 b0 = *(const float4*)(bc + t*64 + 32);
        float4 b1 = *(const float4*)(bc + t*64 + 36);
        float4 b2 = *(const float4*)(bc + t*64 + 40);
        float4 b3 = *(const float4*)(bc + t*64 + 44);
        float4 c0 = *(const float4*)(bc + t*64 + 48);
        float4 c1 = *(const float4*)(bc + t*64 + 52);
        float4 c2 = *(const float4*)(bc + t*64 + 56);
        float4 c3 = *(const float4*)(bc + t*64 + 60);
        float Bv[16] = {b0.x,b0.y,b0.z,b0.w, b1.x,b1.y,b1.z,b1.w,
                        b2.x,b2.y,b2.z,b2.w, b3.x,b3.y,b3.z,b3.w};
        float Cv[16] = {c0.x,c0.y,c0.z,c0.w, c1.x,c1.y,c1.z,c1.w,
                        c2.x,c2.y,c2.z,c2.w, c3.x,c3.y,c3.z,c3.w};
        float y = 0.f;
        #pragma unroll
        for (int s = 0; s < D_STATE; ++s) {
            float e = __expf(dl * A[s]);
            h[s] = fmaf(e, h[s], du * Bv[s]);
            y = fmaf(h[s], Cv[s], y);
        }
        float z = b2f(zp[(size_t)t*2048]);
        float yy = fmaf(ut, Dk, y);
        yp[(size_t)t*D_INNER] = f2b(yy * (z / (1.f + __expf(-z))));
    }
}

// ---------------- fused residual + LayerNorm, dual f32/bf16 out ----------------
__global__ __launch_bounds__(256) void ln_kernel(float* __restrict__ x, const float* __restrict__ t,
                                                 const float* __restrict__ g, const float* __restrict__ bta,
                                                 u16* __restrict__ xbf) {
    int row = blockIdx.x * 4 + (threadIdx.x >> 6);
    int lane = threadIdx.x & 63;
    const float* xr = x + (size_t)row*D_MODEL;
    const float* tr = t + (size_t)row*D_MODEL;
    float v[8];
    float sum = 0.f;
    #pragma unroll
    for (int j = 0; j < 8; ++j) { v[j] = xr[lane + j*64] + tr[lane + j*64]; sum += v[j]; }
    #pragma unroll
    for (int off = 32; off; off >>= 1) sum += __shfl_xor(sum, off);
    float mu = sum * (1.f/512.f);
    float vs = 0.f;
    #pragma unroll
    for (int j = 0; j < 8; ++j) { float dm = v[j] - mu; vs += dm*dm; }
    #pragma unroll
    for (int off = 32; off; off >>= 1) vs += __shfl_xor(vs, off);
    float inv = rsqrtf(vs * (1.f/512.f) + 1e-5f);
    #pragma unroll
    for (int j = 0; j < 8; ++j) {
        int c = lane + j*64;
        float o = (v[j] - mu) * inv * g[c] + bta[c];
        x[(size_t)row*D_MODEL + c] = o;
        xbf[(size_t)row*D_MODEL + c] = f2b(o);
    }
}

// ---------------- MFMA flash attention: S^T = mfma(K,Q), O^T = mfma(V^T, P^T) ----------------
__global__ __launch_bounds__(256) void attn_mfma(const u16* __restrict__ qb, const u16* __restrict__ kb,
                                                 const u16* __restrict__ vt, u16* __restrict__ ob) {
    int bx = blockIdx.x, h = blockIdx.y, b = blockIdx.z;
    int tid = threadIdx.x, lane = tid & 63, w = tid >> 6;
    int l15 = lane & 15, g = lane >> 4;
    __shared__ u16 Ks[32*64];       // [key][dh], 128B rows, XOR swizzled
    __shared__ u16 Vs[64*40];       // [dh][key], 80B rows
    __shared__ u16 Ps[4][16*40];    // per-wave P [q][key], 80B rows
    int qbase = bx*64;
    int qrow = qbase + w*16 + l15;

    const u16* qptr = qb + ((size_t)(b*Ldim + qrow))*D_MODEL + h*DH + g*8;
    bf16x8 qf[2];
    qf[0] = *(const bf16x8*)(qptr);
    qf[1] = *(const bf16x8*)(qptr + 32);

    f32x4 o_acc[4] = {};
    float m_run = -INFINITY, l_run = 0.f;
    int ntiles = bx*2 + 2;

    for (int kt = 0; kt < ntiles; ++kt) {
        __syncthreads();
        {   // stage K tile: 32 keys x 64 dh
            int row = tid >> 3, slot = tid & 7;
            bf16x8 v = *(const bf16x8*)(kb + ((size_t)(b*Ldim + kt*32 + row))*D_MODEL + h*DH + slot*8);
            *(bf16x8*)((char*)Ks + row*128 + ((slot ^ (row&7)) << 4)) = v;
        }
        {   // stage V^T tile: 64 dh x 32 keys
            int row = tid >> 2, slot = tid & 3;
            bf16x8 v = *(const bf16x8*)(vt + ((size_t)(b*D_MODEL + h*DH + row))*Ldim + kt*32 + slot*8);
            *(bf16x8*)((char*)Vs + row*80 + slot*16) = v;
        }
        __syncthreads();

        f32x4 sf[2];
        #pragma unroll
        for (int f = 0; f < 2; ++f) {
            f32x4 a = {0.f, 0.f, 0.f, 0.f};
            #pragma unroll
            for (int ks = 0; ks < 2; ++ks) {
                int row = f*16 + l15;
                bf16x8 kf = *(const bf16x8*)((const char*)Ks + row*128 + (((ks*4+g) ^ (row&7)) << 4));
                a = __builtin_amdgcn_mfma_f32_16x16x32_bf16(kf, qf[ks], a, 0, 0, 0);
            }
            sf[f] = a;
        }

        float pmax = -INFINITY;
        #pragma unroll
        for (int f = 0; f < 2; ++f)
            #pragma unroll
            for (int r = 0; r < 4; ++r) {
                int key = kt*32 + f*16 + g*4 + r;
                float sv = (key <= qrow) ? sf[f][r]*0.125f : -INFINITY;
                sf[f][r] = sv;
                pmax = fmaxf(pmax, sv);
            }
        pmax = fmaxf(pmax, __shfl_xor(pmax, 16));
        pmax = fmaxf(pmax, __shfl_xor(pmax, 32));
        float mnew = fmaxf(m_run, pmax);
        float corr = __expf(m_run - mnew);

        float ps = 0.f;
        #pragma unroll
        for (int f = 0; f < 2; ++f) {
            float p0 = __expf(sf[f][0] - mnew), p1 = __expf(sf[f][1] - mnew);
            float p2 = __expf(sf[f][2] - mnew), p3 = __expf(sf[f][3] - mnew);
            ps += p0 + p1 + p2 + p3;
            u16x4 pk; pk.x = f2b(p0); pk.y = f2b(p1); pk.z = f2b(p2); pk.w = f2b(p3);
            *(u16x4*)((char*)&Ps[w][0] + l15*80 + f*32 + g*8) = pk;
        }
        ps += __shfl_xor(ps, 16);
        ps += __shfl_xor(ps, 32);
        l_run = l_run * corr + ps;
        m_run = mnew;
        #pragma unroll
        for (int t = 0; t < 4; ++t) o_acc[t] *= corr;

        bf16x8 pf = *(const bf16x8*)((const char*)&Ps[w][0] + l15*80 + g*16);
        #pragma unroll
        for (int t = 0; t < 4; ++t) {
            int row = t*16 + l15;
            bf16x8 vf = *(const bf16x8*)((const char*)Vs + row*80 + g*16);
            o_acc[t] = __builtin_amdgcn_mfma_f32_16x16x32_bf16(vf, pf, o_acc[t], 0, 0, 0);
        }
    }

    float invl = 1.f / l_run;
    #pragma unroll
    for (int t = 0; t < 4; ++t) {
        u16x4 o4;
        o4.x = f2b(o_acc[t][0]*invl); o4.y = f2b(o_acc[t][1]*invl);
        o4.z = f2b(o_acc[t][2]*invl); o4.w = f2b(o_acc[t][3]*invl);
        *(u16x4*)(ob + ((size_t)(b*Ldim + qrow))*D_MODEL + h*DH + t*16 + g*4) = o4;
    }
}

extern "C" void kernel_launch(void* const* d_in, const int* in_sizes, int n_in,
                              void* d_out, int out_size, void* d_ws, size_t ws_size,
                              hipStream_t stream) {
    const float* x_dec   = (const float*)d_in[0];
    const float* x_mark  = (const float*)d_in[1];
    const float* token_w = (const float*)d_in[2];
    const float* temp_w  = (const float*)d_in[3];
    const float* in_proj_w = (const float*)d_in[4];
    const float* conv_w  = (const float*)d_in[5];
    const float* conv_b  = (const float*)d_in[6];
    const float* x_proj_w = (const float*)d_in[7];
    const float* dt_w    = (const float*)d_in[8];
    const float* dt_b    = (const float*)d_in[9];
    const float* A_log   = (const float*)d_in[10];
    const float* D_skip  = (const float*)d_in[11];
    const float* out_w_m = (const float*)d_in[12];
    const float* wq = (const float*)d_in[13];
    const float* bq = (const float*)d_in[14];
    const float* wk = (const float*)d_in[15];
    const float* bk = (const float*)d_in[16];
    const float* wv = (const float*)d_in[17];
    const float* bv = (const float*)d_in[18];
    const float* wo = (const float*)d_in[19];
    const float* bo = (const float*)d_in[20];
    const float* ln1_g = (const float*)d_in[21];
    const float* ln1_b = (const float*)d_in[22];
    const float* ln2_g = (const float*)d_in[23];
    const float* ln2_b = (const float*)d_in[24];
    const float* proj_w = (const float*)d_in[25];
    const float* proj_b = (const float*)d_in[26];

    if (ws_size < 152*MB) return;

    char* wsb = (char*)d_ws;
    float* x     = (float*)(wsb + 0);          // 16MB
    u16*   xbf   = (u16*)(wsb + 16*MB);        // 8MB
    u16*   xzb   = (u16*)(wsb + 24*MB);        // 32MB (aliased by q/k/vt/o after scan)
    u16*   qbf   = (u16*)(wsb + 24*MB);        // 8MB
    u16*   kbf   = (u16*)(wsb + 32*MB);        // 8MB
    u16*   vtb   = (u16*)(wsb + 40*MB);        // 8MB
    u16*   obf   = (u16*)(wsb + 48*MB);        // 8MB
    u16*   ucb   = (u16*)(wsb + 56*MB);        // 16MB
    float* hend  = (float*)(wsb + 72*MB);      // 8MB
    float* aprod = (float*)(wsb + 80*MB);      // 8MB
    float* dbc   = (float*)(wsb + 88*MB);      // 2MB
    u16*   dtb   = (u16*)(wsb + 90*MB);        // 0.5MB
    float* delta = (float*)(wsb + 91*MB);      // 32MB
    float* tmp   = delta;                      // alias: delta dead when tmp used
    u16*   ysb   = (u16*)(wsb + 123*MB);       // 16MB
    u16*   iprT  = (u16*)(wsb + 139*MB);       // 4MB
    u16*   outT  = (u16*)(wsb + 143*MB);       // 2MB
    u16*   qT    = (u16*)(wsb + 145*MB);       // 1MB
    u16*   kT    = (u16*)(wsb + 146*MB);       // 1MB
    u16*   vT    = (u16*)(wsb + 147*MB);       // 1MB
    u16*   oT    = (u16*)(wsb + 148*MB);       // 1MB
    u16*   xprT  = (u16*)(wsb + 149*MB);       // 256KB (2 x 64x1024)
    u16*   dtwT  = (u16*)(wsb + 150*MB);       // 128KB (2 x 1024x32)
    float* out   = (float*)d_out;

    transpose_cast<<<dim3(32, 8, 2), 256, 0, stream>>>(in_proj_w, iprT, 512, 2048);
    transpose_cast<<<dim3(8, 16, 2), 256, 0, stream>>>(out_w_m, outT, 1024, 512);
    transpose_cast<<<dim3(8, 8, 2), 256, 0, stream>>>(wq, qT, 512, 512);
    transpose_cast<<<dim3(8, 8, 2), 256, 0, stream>>>(wk, kT, 512, 512);
    transpose_cast<<<dim3(8, 8, 2), 256, 0, stream>>>(wv, vT, 512, 512);
    transpose_cast<<<dim3(8, 8, 2), 256, 0, stream>>>(wo, oT, 512, 512);
    transpose_cast<<<dim3(1, 16, 2), 256, 0, stream>>>(x_proj_w, xprT, 1024, 64);
    dtw_transpose<<<256, 256, 0, stream>>>(dt_w, dtwT);

    embed_kernel<<<ROWS, 256, 0, stream>>>(x_dec, x_mark, token_w, temp_w, x, xbf);

    for (int i = 0; i < 2; ++i) {
        // xz = x @ in_proj   (8192 x 2048 x 512), bf16 out
        gemm_bf16<1,0><<<dim3(16,64), 256, 0, stream>>>(xbf, 512, iprT + (size_t)i*2048*512, 512,
                                                        nullptr, xzb, 2048, 2048, 512, 512);
        conv_silu_kernel<<<(ROWS*128)/256, 256, 0, stream>>>(xzb, conv_w + i*D_INNER*D_CONV,
                                                             conv_b + i*D_INNER, ucb);
        // dbc = uc @ x_proj  (8192 x 64 x 1024), f32 + dt slice bf16
        xproj_kernel<<<ROWS/64, 256, 0, stream>>>(ucb, xprT + (size_t)i*64*1024, dbc, dtb);
        // delta = softplus(dt @ dt_w + dt_b)  (8192 x 1024 x 32), MFMA, K-pad 64
        gemm_bf16<0,1><<<dim3(8,64), 256, 0, stream>>>(dtb, 32, dtwT + (size_t)i*1024*32, 32,
                                                       dt_b + i*D_INNER, delta, 1024, 1024, 64, 32);
        // chunked scan (3 passes) + fused skip/gate
        scan_part1<<<dim3(32, NCHUNK), 256, 0, stream>>>(delta, ucb, dbc, A_log + i*D_INNER*D_STATE,
                                                         hend, aprod);
        scan_part2<<<(ROWS*D_STATE)/256, 256, 0, stream>>>(hend, aprod);
        scan_part3<<<dim3(32, NCHUNK), 256, 0, stream>>>(delta, ucb, dbc, A_log + i*D_INNER*D_STATE,
                                                         hend, xzb, D_skip + i*D_INNER, ysb);
        // tmp = ys @ out_w   (8192 x 512 x 1024), f32 out
        gemm_bf16<0,0><<<dim3(4,64), 256, 0, stream>>>(ysb, 1024, outT + (size_t)i*512*1024, 1024,
                                                       nullptr, tmp, 512, 512, 1024, 1024);
        ln_kernel<<<ROWS/4, 256, 0, stream>>>(x, tmp, ln1_g + i*512, ln1_b + i*512, xbf);
        gemm_bf16<1,0><<<dim3(4,64), 256, 0, stream>>>(xbf, 512, qT + (size_t)i*512*512, 512,
                                                       bq + i*512, qbf, 512, 512, 512, 512);
        gemm_bf16<1,0><<<dim3(4,64), 256, 0, stream>>>(xbf, 512, kT + (size_t)i*512*512, 512,
                                                       bk + i*512, kbf, 512, 512, 512, 512);
        gemm_bf16<2,0><<<dim3(4,64), 256, 0, stream>>>(xbf, 512, vT + (size_t)i*512*512, 512,
                                                       bv + i*512, vtb, 512, 512, 512, 512);
        attn_mfma<<<dim3(Ldim/64, N_HEADS, Bdim), 256, 0, stream>>>(qbf, kbf, vtb, obf);
        gemm_bf16<0,0><<<dim3(4,64), 256, 0, stream>>>(obf, 512, oT + (size_t)i*512*512, 512,
                                                       bo + i*512, tmp, 512, 512, 512, 512);
        ln_kernel<<<ROWS/4, 256, 0, stream>>>(x, tmp, ln2_g + i*512, ln2_b + i*512, xbf);
    }
    proj_kernel<<<ROWS/4, 256, 0, stream>>>(x, proj_w, proj_b, out);
}

// Round 6
// 899.634 us; speedup vs baseline: 6.8545x; 1.0717x over previous
//
#include <hip/hip_runtime.h>
#include <math.h>

#define Bdim 8
#define Ldim 1024
#define DEC_IN 7
#define D_MODEL 512
#define MARK 4
#define D_INNER 1024
#define D_STATE 16
#define D_CONV 4
#define DT_RANK 32
#define N_HEADS 8
#define DH 64
#define ROWS (Bdim*Ldim)   // 8192
#define MB (1ull<<20)
#define NCHUNK 16
#define CLEN 64            // Ldim / NCHUNK

typedef unsigned short u16;
typedef unsigned int u32;
typedef __attribute__((ext_vector_type(8))) short bf16x8;
typedef __attribute__((ext_vector_type(4))) float f32x4;
typedef __attribute__((ext_vector_type(4))) unsigned short u16x4;

__device__ inline float b2f(u16 u) {
    union { u32 i; float f; } c; c.i = ((u32)u) << 16; return c.f;
}
__device__ inline u16 f2b(float f) {
    union { float f; u32 u; } c; c.f = f;
    u32 u = c.u;
    u32 r = (u + 0x7fffu + ((u >> 16) & 1u)) >> 16;
    return (u16)r;
}
__device__ inline void gload16(const void* g, void* l) {
    __builtin_amdgcn_global_load_lds((const __attribute__((address_space(1))) void*)g,
                                     (__attribute__((address_space(3))) void*)l, 16, 0, 0);
}

// ---------------- embed: token circular conv3 + pos embed + mark proj (dual f32/bf16 out) ----------------
__global__ void embed_kernel(const float* __restrict__ xd, const float* __restrict__ xmark,
                             const float* __restrict__ token_w, const float* __restrict__ temp_w,
                             float* __restrict__ x, u16* __restrict__ xbf) {
    int bt = blockIdx.x;            // 0..8191
    int b = bt >> 10, t = bt & 1023;
    __shared__ float xr[3][DEC_IN];
    __shared__ float mk[MARK];
    if (threadIdx.x < 3*DEC_IN) {
        int k = threadIdx.x / DEC_IN, c = threadIdx.x % DEC_IN;
        int tt = (t + k - 1 + Ldim) % Ldim;
        xr[k][c] = xd[((size_t)b*Ldim + tt)*DEC_IN + c];
    }
    if (threadIdx.x < MARK) mk[threadIdx.x] = xmark[((size_t)b*Ldim + t)*MARK + threadIdx.x];
    __syncthreads();
    for (int dd = threadIdx.x; dd < D_MODEL; dd += 256) {
        float acc = 0.f;
        #pragma unroll
        for (int k = 0; k < 3; ++k)
            #pragma unroll
            for (int c = 0; c < DEC_IN; ++c)
                acc += xr[k][c] * token_w[(k*DEC_IN + c)*D_MODEL + dd];
        int i2 = dd & ~1;
        float freq = expf(-(float)i2 * (logf(10000.f) / (float)D_MODEL));
        float ang = (float)t * freq;
        acc += (dd & 1) ? cosf(ang) : sinf(ang);
        #pragma unroll
        for (int m = 0; m < MARK; ++m) acc += mk[m] * temp_w[m*D_MODEL + dd];
        x[(size_t)bt*D_MODEL + dd] = acc;
        xbf[(size_t)bt*D_MODEL + dd] = f2b(acc);
    }
}

// ---------------- weight transpose + cast: W[K][N] f32 -> Wt[N][K] bf16 (K,N mult of 64) ----------------
__global__ __launch_bounds__(256) void transpose_cast(const float* __restrict__ W, u16* __restrict__ Wt,
                                                      int K, int N, int srcZ, int dstZ) {
    const float* Wz = W + (size_t)blockIdx.z * srcZ;
    u16* Wtz = Wt + (size_t)blockIdx.z * dstZ;
    __shared__ u16 tile[64][72];
    int k0 = blockIdx.y*64, n0 = blockIdx.x*64;
    int tid = threadIdx.x;
    #pragma unroll
    for (int it = 0; it < 16; ++it) {
        int idx = it*256 + tid; int kr = idx>>6, nc = idx&63;
        tile[kr][nc] = f2b(Wz[(size_t)(k0+kr)*N + n0 + nc]);
    }
    __syncthreads();
    #pragma unroll
    for (int it = 0; it < 2; ++it) {
        int idx = it*256 + tid; int nr = idx>>3, slot = idx&7;
        bf16x8 v;
        #pragma unroll
        for (int j = 0; j < 8; ++j) ((u16*)&v)[j] = tile[slot*8+j][nr];
        *(bf16x8*)(Wtz + (size_t)(n0+nr)*K + k0 + slot*8) = v;
    }
}

// ---------------- dt_w transpose+pad: [2][32][1024] f32 -> [2][1024][64] bf16 (zero k>=32) ----------------
__global__ void dtw_transpose(const float* __restrict__ dt_w, u16* __restrict__ dtwT) {
    int idx = blockIdx.x*256 + threadIdx.x;   // 0..131071
    int z = idx >> 16, rem = idx & 65535;
    int n = rem >> 6, k = rem & 63;
    dtwT[idx] = (k < 32) ? f2b(dt_w[(size_t)z*32768 + k*1024 + n]) : (u16)0;
}

// ---------------- pack q/k/v bias: [2][1536] ----------------
__global__ void pack_bias(const float* __restrict__ bq, const float* __restrict__ bk,
                          const float* __restrict__ bv, float* __restrict__ dst) {
    int idx = blockIdx.x*256 + threadIdx.x;   // 0..3071
    int layer = idx / 1536, c = idx % 1536;
    const float* src = (c < 512) ? bq : (c < 1024) ? bk : bv;
    dst[idx] = src[layer*512 + (c & 511)];
}

// ---------------- bf16 MFMA GEMM: C = A@Bt^T (+bias)(+act) ----------------
// 128x128 tile, BK=64, global_load_lds staging, linear LDS, XCD-chunked swizzle.
// OUTMODE: 1 = bf16 out, 3 = qkv split (col<1024 -> qk, col>=1024 -> vt transposed)
// ACT: 0 = none, 1 = softplus. Grid is 1D (nwg = gridX * gridY, nwg % 8 == 0).
template<int OUTMODE, int ACT>
__global__ __launch_bounds__(256) void gemm_bf16(const u16* __restrict__ A, int lda,
                                                 const u16* __restrict__ Bt, int ldb,
                                                 const float* __restrict__ bias, void* __restrict__ Cp,
                                                 int ldc, int gridX, int N, int K,
                                                 u16* __restrict__ vt) {
    __shared__ u16 As[128*64];
    __shared__ u16 Bs[128*64];
    int tid = threadIdx.x;
    int nwg = gridDim.x, q8 = nwg >> 3;
    int bid = blockIdx.x;
    int wg = (bid & 7)*q8 + (bid >> 3);          // XCD-chunked swizzle
    int bx = wg % gridX, by = wg / gridX;
    int bm = by*128, bn = bx*128;
    int lane = tid & 63, wv = tid >> 6;
    int rm = (wv & 1)*64, cn = (wv >> 1)*64;
    int l15 = lane & 15, g = lane >> 4;
    int lrow = lane >> 3, lcol = (lane & 7)*8;

    f32x4 acc[4][4] = {};

    for (int k0 = 0; k0 < K; k0 += 64) {
        __syncthreads();
        #pragma unroll
        for (int it = 0; it < 4; ++it) {
            int r0 = wv*32 + it*8;
            gload16(A  + (size_t)(bm + r0 + lrow)*lda + k0 + lcol, As + r0*64);
            gload16(Bt + (size_t)(bn + r0 + lrow)*ldb + k0 + lcol, Bs + r0*64);
        }
        __syncthreads();
        #pragma unroll
        for (int ks = 0; ks < 2; ++ks) {
            bf16x8 af[4], bfr[4];
            #pragma unroll
            for (int m = 0; m < 4; ++m) {
                af[m]  = *(const bf16x8*)(As + (rm + m*16 + l15)*64 + (ks*4+g)*8);
                bfr[m] = *(const bf16x8*)(Bs + (cn + m*16 + l15)*64 + (ks*4+g)*8);
            }
            #pragma unroll
            for (int m = 0; m < 4; ++m)
                #pragma unroll
                for (int n = 0; n < 4; ++n)
                    acc[m][n] = __builtin_amdgcn_mfma_f32_16x16x32_bf16(af[m], bfr[n], acc[m][n], 0, 0, 0);
        }
    }

    float bv4[4];
    #pragma unroll
    for (int n = 0; n < 4; ++n) bv4[n] = bias ? bias[bn + cn + n*16 + l15] : 0.f;

    #pragma unroll
    for (int m = 0; m < 4; ++m) {
        #pragma unroll
        for (int n = 0; n < 4; ++n) {
            int col = bn + cn + n*16 + l15;
            #pragma unroll
            for (int r = 0; r < 4; ++r) {
                int row = bm + rm + m*16 + g*4 + r;
                float v = acc[m][n][r] + bv4[n];
                if (ACT == 1) v = (v > 20.f) ? v : log1pf(__expf(v));
                if (OUTMODE == 1) {
                    ((u16*)Cp)[(size_t)row*ldc + col] = f2b(v);
                } else {   // OUTMODE 3: qkv split
                    int b = row >> 10, t = row & 1023;
                    if (col < 1024) ((u16*)Cp)[(size_t)row*ldc + col] = f2b(v);
                    else vt[((size_t)(b*D_MODEL) + (col - 1024))*Ldim + t] = f2b(v);
                }
            }
        }
    }
}

// ---------------- x_proj MFMA: dbc = ucb @ xprT^T (8192x64x1024), f32 dbc + bf16 dtb (64-wide, padded) ----------------
__global__ __launch_bounds__(256) void xproj_kernel(const u16* __restrict__ ucb, const u16* __restrict__ xprT,
                                                    float* __restrict__ dbc, u16* __restrict__ dtb) {
    __shared__ u16 As[64*64];
    __shared__ u16 Bs[64*64];
    int tid = threadIdx.x, lane = tid & 63, wv = tid >> 6;
    int l15 = lane & 15, g = lane >> 4;
    int bm = blockIdx.x*64;
    f32x4 acc[4] = {};
    for (int k0 = 0; k0 < 1024; k0 += 64) {
        __syncthreads();
        #pragma unroll
        for (int it = 0; it < 2; ++it) {
            int idx = it*256 + tid; int row = idx >> 3, slot = idx & 7;
            bf16x8 av = *(const bf16x8*)(ucb + (size_t)(bm+row)*1024 + k0 + slot*8);
            *(bf16x8*)((char*)As + row*128 + ((slot ^ (row&7)) << 4)) = av;
            bf16x8 bv = *(const bf16x8*)(xprT + (size_t)row*1024 + k0 + slot*8);
            *(bf16x8*)((char*)Bs + row*128 + ((slot ^ (row&7)) << 4)) = bv;
        }
        __syncthreads();
        #pragma unroll
        for (int ks = 0; ks < 2; ++ks) {
            int arow = wv*16 + l15;
            bf16x8 af = *(const bf16x8*)((const char*)As + arow*128 + (((ks*4+g) ^ (arow&7)) << 4));
            #pragma unroll
            for (int n = 0; n < 4; ++n) {
                int col = n*16 + l15;
                bf16x8 bfr = *(const bf16x8*)((const char*)Bs + col*128 + (((ks*4+g) ^ (col&7)) << 4));
                acc[n] = __builtin_amdgcn_mfma_f32_16x16x32_bf16(af, bfr, acc[n], 0, 0, 0);
            }
        }
    }
    #pragma unroll
    for (int n = 0; n < 4; ++n) {
        int col = n*16 + l15;
        #pragma unroll
        for (int r = 0; r < 4; ++r) {
            int row = bm + wv*16 + g*4 + r;
            float v = acc[n][r];
            dbc[(size_t)row*64 + col] = v;
            dtb[(size_t)row*64 + col] = (col < 32) ? f2b(v) : (u16)0;
        }
    }
}

// ---------------- final proj: out = x @ proj_w + proj_b (wave per row, N=7) ----------------
__global__ __launch_bounds__(256) void proj_kernel(const float* __restrict__ x, const float* __restrict__ w,
                                                   const float* __restrict__ pb, float* __restrict__ out) {
    int row = blockIdx.x*4 + (threadIdx.x >> 6);
    int lane = threadIdx.x & 63;
    const float* xr = x + (size_t)row*D_MODEL + lane*8;
    float xv[8];
    #pragma unroll
    for (int j = 0; j < 8; ++j) xv[j] = xr[j];
    const float* wr = w + lane*56;
    float acc[7] = {0,0,0,0,0,0,0};
    #pragma unroll
    for (int j = 0; j < 8; ++j)
        #pragma unroll
        for (int c = 0; c < 7; ++c) acc[c] = fmaf(xv[j], wr[j*7 + c], acc[c]);
    #pragma unroll
    for (int c = 0; c < 7; ++c) {
        #pragma unroll
        for (int off = 32; off; off >>= 1) acc[c] += __shfl_xor(acc[c], off);
    }
    if (lane < 7) out[(size_t)row*7 + lane] = acc[lane] + pb[lane];
}

// ---------------- causal conv1d (k=4) + SiLU, vectorized weights ----------------
__global__ void conv_silu_kernel(const u16* __restrict__ xz, const float* __restrict__ conv_w,
                                 const float* __restrict__ conv_b, u16* __restrict__ ucb) {
    int idx = blockIdx.x*256 + threadIdx.x;   // over ROWS*128
    int d8 = idx & 127, bt = idx >> 7;
    int t = bt & 1023, b = bt >> 10;
    int d0 = d8*8;
    float4 cb0 = *(const float4*)(conv_b + d0);
    float4 cb1 = *(const float4*)(conv_b + d0 + 4);
    float acc[8] = {cb0.x,cb0.y,cb0.z,cb0.w, cb1.x,cb1.y,cb1.z,cb1.w};
    float w[8][4];
    #pragma unroll
    for (int j = 0; j < 8; ++j) *(float4*)&w[j][0] = *(const float4*)(conv_w + (d0+j)*4);
    #pragma unroll
    for (int k = 0; k < 4; ++k) {
        int tt = t + k - 3;
        if (tt >= 0) {
            bf16x8 v = *(const bf16x8*)(xz + ((size_t)(b*Ldim + tt))*2048 + d0);
            #pragma unroll
            for (int j = 0; j < 8; ++j)
                acc[j] = fmaf(b2f(((u16*)&v)[j]), w[j][k], acc[j]);
        }
    }
    bf16x8 o;
    #pragma unroll
    for (int j = 0; j < 8; ++j) {
        float s = acc[j] / (1.f + __expf(-acc[j]));
        ((u16*)&o)[j] = f2b(s);
    }
    *(bf16x8*)(ucb + (size_t)bt*1024 + d0) = o;
}

// ---------------- chunked selective scan, pass 1 ----------------
__global__ __launch_bounds__(256) void scan_part1(const u16* __restrict__ delta,
                                                  const u16* __restrict__ ucb,
                                                  const float* __restrict__ dbc,
                                                  const float* __restrict__ A_log,
                                                  float* __restrict__ hend,
                                                  float* __restrict__ aprod) {
    int c = blockIdx.y;
    int bd = blockIdx.x*256 + threadIdx.x;   // 0..8191
    int d = bd & 1023, b = bd >> 10;
    float A[D_STATE], h[D_STATE], ap[D_STATE];
    #pragma unroll
    for (int s = 0; s < D_STATE; ++s) { A[s] = -__expf(A_log[d*D_STATE + s]); h[s] = 0.f; ap[s] = 1.f; }
    const u16*   dptr = delta + (size_t)b*Ldim*D_INNER + d;
    const u16*   uptr = ucb   + (size_t)b*Ldim*D_INNER + d;
    const float* bc   = dbc   + (size_t)b*Ldim*64;
    for (int tt = 0; tt < CLEN; ++tt) {
        int t = c*CLEN + tt;
        float dl = b2f(dptr[(size_t)t*D_INNER]);
        float ut = b2f(uptr[(size_t)t*D_INNER]);
        float du = dl * ut;
        float4 b0 = *(const float4*)(bc + t*64 + 32);
        float4 b1 = *(const float4*)(bc + t*64 + 36);
        float4 b2 = *(const float4*)(bc + t*64 + 40);
        float4 b3 = *(const float4*)(bc + t*64 + 44);
        float Bv[16] = {b0.x,b0.y,b0.z,b0.w, b1.x,b1.y,b1.z,b1.w,
                        b2.x,b2.y,b2.z,b2.w, b3.x,b3.y,b3.z,b3.w};
        #pragma unroll
        for (int s = 0; s < D_STATE; ++s) {
            float e = __expf(dl * A[s]);
            h[s] = fmaf(e, h[s], du * Bv[s]);
            ap[s] *= e;
        }
    }
    size_t o = ((size_t)c*ROWS + bd)*D_STATE;
    #pragma unroll
    for (int q = 0; q < 4; ++q) {
        *(float4*)(hend  + o + q*4) = make_float4(h[q*4],  h[q*4+1],  h[q*4+2],  h[q*4+3]);
        *(float4*)(aprod + o + q*4) = make_float4(ap[q*4], ap[q*4+1], ap[q*4+2], ap[q*4+3]);
    }
}

// ---------------- pass 2: combine chunk states ----------------
__global__ __launch_bounds__(256) void scan_part2(float* __restrict__ hend,
                                                  const float* __restrict__ aprod) {
    int idx = blockIdx.x*256 + threadIdx.x;  // 0..131071
    float hin = 0.f;
    #pragma unroll
    for (int c = 0; c < NCHUNK; ++c) {
        size_t o = (size_t)c*ROWS*D_STATE + idx;
        float he = hend[o], ap = aprod[o];
        hend[o] = hin;
        hin = fmaf(ap, hin, he);
    }
}

// ---------------- pass 3: replay from h_in, fused skip + silu(z) gate, bf16 out ----------------
__global__ __launch_bounds__(256) void scan_part3(const u16* __restrict__ delta,
                                                  const u16* __restrict__ ucb,
                                                  const float* __restrict__ dbc,
                                                  const float* __restrict__ A_log,
                                                  const float* __restrict__ hend,
                                                  const u16* __restrict__ xz,
                                                  const float* __restrict__ Dskip,
                                                  u16* __restrict__ ysb) {
    int c = blockIdx.y;
    int bd = blockIdx.x*256 + threadIdx.x;
    int d = bd & 1023, b = bd >> 10;
    float A[D_STATE], h[D_STATE];
    size_t o = ((size_t)c*ROWS + bd)*D_STATE;
    #pragma unroll
    for (int s = 0; s < D_STATE; ++s) {
        A[s] = -__expf(A_log[d*D_STATE + s]);
        h[s] = hend[o + s];
    }
    float Dk = Dskip[d];
    const u16*   dptr = delta + (size_t)b*Ldim*D_INNER + d;
    const u16*   uptr = ucb   + (size_t)b*Ldim*D_INNER + d;
    const float* bc   = dbc   + (size_t)b*Ldim*64;
    const u16*   zp   = xz    + (size_t)b*Ldim*2048 + 1024 + d;
    u16* yp = ysb + (size_t)b*Ldim*D_INNER + d;
    for (int tt = 0; tt < CLEN; ++tt) {
        int t = c*CLEN + tt;
        float dl = b2f(dptr[(size_t)t*D_INNER]);
        float ut = b2f(uptr[(size_t)t*D_INNER]);
        float du = dl * ut;
        float4 b0 = *(const float4*)(bc + t*64 + 32);
        float4 b1 = *(const float4*)(bc + t*64 + 36);
        float4 b2 = *(const float4*)(bc + t*64 + 40);
        float4 b3 = *(const float4*)(bc + t*64 + 44);
        float4 c0 = *(const float4*)(bc + t*64 + 48);
        float4 c1 = *(const float4*)(bc + t*64 + 52);
        float4 c2 = *(const float4*)(bc + t*64 + 56);
        float4 c3 = *(const float4*)(bc + t*64 + 60);
        float Bv[16] = {b0.x,b0.y,b0.z,b0.w, b1.x,b1.y,b1.z,b1.w,
                        b2.x,b2.y,b2.z,b2.w, b3.x,b3.y,b3.z,b3.w};
        float Cv[16] = {c0.x,c0.y,c0.z,c0.w, c1.x,c1.y,c1.z,c1.w,
                        c2.x,c2.y,c2.z,c2.w, c3.x,c3.y,c3.z,c3.w};
        float y = 0.f;
        #pragma unroll
        for (int s = 0; s < D_STATE; ++s) {
            float e = __expf(dl * A[s]);
            h[s] = fmaf(e, h[s], du * Bv[s]);
            y = fmaf(h[s], Cv[s], y);
        }
        float z = b2f(zp[(size_t)t*2048]);
        float yy = fmaf(ut, Dk, y);
        yp[(size_t)t*D_INNER] = f2b(yy * (z / (1.f + __expf(-z))));
    }
}

// ---------------- fused residual + LayerNorm (tmp bf16), dual f32/bf16 out ----------------
__global__ __launch_bounds__(256) void ln_kernel(float* __restrict__ x, const u16* __restrict__ t,
                                                 const float* __restrict__ g, const float* __restrict__ bta,
                                                 u16* __restrict__ xbf) {
    int row = blockIdx.x * 4 + (threadIdx.x >> 6);
    int lane = threadIdx.x & 63;
    const float* xr = x + (size_t)row*D_MODEL;
    const u16*   tr = t + (size_t)row*D_MODEL;
    float v[8];
    float sum = 0.f;
    #pragma unroll
    for (int j = 0; j < 8; ++j) { v[j] = xr[lane + j*64] + b2f(tr[lane + j*64]); sum += v[j]; }
    #pragma unroll
    for (int off = 32; off; off >>= 1) sum += __shfl_xor(sum, off);
    float mu = sum * (1.f/512.f);
    float vs = 0.f;
    #pragma unroll
    for (int j = 0; j < 8; ++j) { float dm = v[j] - mu; vs += dm*dm; }
    #pragma unroll
    for (int off = 32; off; off >>= 1) vs += __shfl_xor(vs, off);
    float inv = rsqrtf(vs * (1.f/512.f) + 1e-5f);
    #pragma unroll
    for (int j = 0; j < 8; ++j) {
        int c = lane + j*64;
        float o = (v[j] - mu) * inv * g[c] + bta[c];
        x[(size_t)row*D_MODEL + c] = o;
        xbf[(size_t)row*D_MODEL + c] = f2b(o);
    }
}

// ---------------- MFMA flash attention: S^T = mfma(K,Q), O^T = mfma(V^T, P^T) ----------------
// q,k packed in one buffer qk[bt][1024]: q cols 0..511, k cols 512..1023.
__global__ __launch_bounds__(256) void attn_mfma(const u16* __restrict__ qk,
                                                 const u16* __restrict__ vt, u16* __restrict__ ob) {
    int bx = blockIdx.x, h = blockIdx.y, b = blockIdx.z;
    int tid = threadIdx.x, lane = tid & 63, w = tid >> 6;
    int l15 = lane & 15, g = lane >> 4;
    __shared__ u16 Ks[32*64];       // [key][dh], 128B rows, XOR swizzled
    __shared__ u16 Vs[64*40];       // [dh][key], 80B rows
    __shared__ u16 Ps[4][16*40];    // per-wave P [q][key], 80B rows
    int qbase = bx*64;
    int qrow = qbase + w*16 + l15;

    const u16* qptr = qk + ((size_t)(b*Ldim + qrow))*1024 + h*DH + g*8;
    bf16x8 qf[2];
    qf[0] = *(const bf16x8*)(qptr);
    qf[1] = *(const bf16x8*)(qptr + 32);

    f32x4 o_acc[4] = {};
    float m_run = -INFINITY, l_run = 0.f;
    int ntiles = bx*2 + 2;

    for (int kt = 0; kt < ntiles; ++kt) {
        __syncthreads();
        {   // stage K tile: 32 keys x 64 dh
            int row = tid >> 3, slot = tid & 7;
            bf16x8 v = *(const bf16x8*)(qk + ((size_t)(b*Ldim + kt*32 + row))*1024 + 512 + h*DH + slot*8);
            *(bf16x8*)((char*)Ks + row*128 + ((slot ^ (row&7)) << 4)) = v;
        }
        {   // stage V^T tile: 64 dh x 32 keys
            int row = tid >> 2, slot = tid & 3;
            bf16x8 v = *(const bf16x8*)(vt + ((size_t)(b*D_MODEL + h*DH + row))*Ldim + kt*32 + slot*8);
            *(bf16x8*)((char*)Vs + row*80 + slot*16) = v;
        }
        __syncthreads();

        f32x4 sf[2];
        #pragma unroll
        for (int f = 0; f < 2; ++f) {
            f32x4 a = {0.f, 0.f, 0.f, 0.f};
            #pragma unroll
            for (int ks = 0; ks < 2; ++ks) {
                int row = f*16 + l15;
                bf16x8 kf = *(const bf16x8*)((const char*)Ks + row*128 + (((ks*4+g) ^ (row&7)) << 4));
                a = __builtin_amdgcn_mfma_f32_16x16x32_bf16(kf, qf[ks], a, 0, 0, 0);
            }
            sf[f] = a;
        }

        float pmax = -INFINITY;
        #pragma unroll
        for (int f = 0; f < 2; ++f)
            #pragma unroll
            for (int r = 0; r < 4; ++r) {
                int key = kt*32 + f*16 + g*4 + r;
                float sv = (key <= qrow) ? sf[f][r]*0.125f : -INFINITY;
                sf[f][r] = sv;
                pmax = fmaxf(pmax, sv);
            }
        pmax = fmaxf(pmax, __shfl_xor(pmax, 16));
        pmax = fmaxf(pmax, __shfl_xor(pmax, 32));
        float mnew = fmaxf(m_run, pmax);
        float corr = __expf(m_run - mnew);

        float ps = 0.f;
        #pragma unroll
        for (int f = 0; f < 2; ++f) {
            float p0 = __expf(sf[f][0] - mnew), p1 = __expf(sf[f][1] - mnew);
            float p2 = __expf(sf[f][2] - mnew), p3 = __expf(sf[f][3] - mnew);
            ps += p0 + p1 + p2 + p3;
            u16x4 pk; pk.x = f2b(p0); pk.y = f2b(p1); pk.z = f2b(p2); pk.w = f2b(p3);
            *(u16x4*)((char*)&Ps[w][0] + l15*80 + f*32 + g*8) = pk;
        }
        ps += __shfl_xor(ps, 16);
        ps += __shfl_xor(ps, 32);
        l_run = l_run * corr + ps;
        m_run = mnew;
        #pragma unroll
        for (int t = 0; t < 4; ++t) o_acc[t] *= corr;

        bf16x8 pf = *(const bf16x8*)((const char*)&Ps[w][0] + l15*80 + g*16);
        #pragma unroll
        for (int t = 0; t < 4; ++t) {
            int row = t*16 + l15;
            bf16x8 vf = *(const bf16x8*)((const char*)Vs + row*80 + g*16);
            o_acc[t] = __builtin_amdgcn_mfma_f32_16x16x32_bf16(vf, pf, o_acc[t], 0, 0, 0);
        }
    }

    float invl = 1.f / l_run;
    #pragma unroll
    for (int t = 0; t < 4; ++t) {
        u16x4 o4;
        o4.x = f2b(o_acc[t][0]*invl); o4.y = f2b(o_acc[t][1]*invl);
        o4.z = f2b(o_acc[t][2]*invl); o4.w = f2b(o_acc[t][3]*invl);
        *(u16x4*)(ob + ((size_t)(b*Ldim + qrow))*D_MODEL + h*DH + t*16 + g*4) = o4;
    }
}

extern "C" void kernel_launch(void* const* d_in, const int* in_sizes, int n_in,
                              void* d_out, int out_size, void* d_ws, size_t ws_size,
                              hipStream_t stream) {
    const float* x_dec   = (const float*)d_in[0];
    const float* x_mark  = (const float*)d_in[1];
    const float* token_w = (const float*)d_in[2];
    const float* temp_w  = (const float*)d_in[3];
    const float* in_proj_w = (const float*)d_in[4];
    const float* conv_w  = (const float*)d_in[5];
    const float* conv_b  = (const float*)d_in[6];
    const float* x_proj_w = (const float*)d_in[7];
    const float* dt_w    = (const float*)d_in[8];
    const float* dt_b    = (const float*)d_in[9];
    const float* A_log   = (const float*)d_in[10];
    const float* D_skip  = (const float*)d_in[11];
    const float* out_w_m = (const float*)d_in[12];
    const float* wq = (const float*)d_in[13];
    const float* bq = (const float*)d_in[14];
    const float* wk = (const float*)d_in[15];
    const float* bk = (const float*)d_in[16];
    const float* wv = (const float*)d_in[17];
    const float* bv = (const float*)d_in[18];
    const float* wo = (const float*)d_in[19];
    const float* bo = (const float*)d_in[20];
    const float* ln1_g = (const float*)d_in[21];
    const float* ln1_b = (const float*)d_in[22];
    const float* ln2_g = (const float*)d_in[23];
    const float* ln2_b = (const float*)d_in[24];
    const float* proj_w = (const float*)d_in[25];
    const float* proj_b = (const float*)d_in[26];

    if (ws_size < 150*MB) return;

    char* wsb = (char*)d_ws;
    float* x     = (float*)(wsb + 0);          // 16MB
    u16*   xbf   = (u16*)(wsb + 16*MB);        // 8MB
    u16*   xzb   = (u16*)(wsb + 24*MB);        // 32MB (aliased by qk/obf after scan)
    u16*   qk    = (u16*)(wsb + 24*MB);        // 16MB  [8192][1024]
    u16*   obf   = (u16*)(wsb + 40*MB);        // 8MB
    u16*   vtb   = (u16*)(wsb + 56*MB);        // 8MB
    u16*   ucb   = (u16*)(wsb + 64*MB);        // 16MB
    float* hend  = (float*)(wsb + 80*MB);      // 8MB
    float* aprod = (float*)(wsb + 88*MB);      // 8MB
    float* dbc   = (float*)(wsb + 96*MB);      // 2MB
    u16*   dtb   = (u16*)(wsb + 98*MB);        // 1MB  [8192][64] padded
    u16*   delta = (u16*)(wsb + 100*MB);       // 16MB bf16
    u16*   tmp   = delta;                      // alias: delta dead when tmp used
    u16*   ysb   = (u16*)(wsb + 116*MB);       // 16MB
    u16*   iprT  = (u16*)(wsb + 132*MB);       // 4MB
    u16*   outT  = (u16*)(wsb + 136*MB);       // 2MB
    u16*   qkvT  = (u16*)(wsb + 138*MB);       // 3MB  [2][1536][512]
    u16*   oT    = (u16*)(wsb + 141*MB);       // 1MB
    u16*   xprT  = (u16*)(wsb + 142*MB);       // 256KB
    u16*   dtwT  = (u16*)(wsb + 143*MB);       // 256KB [2][1024][64] padded
    float* biasP = (float*)(wsb + 144*MB);     // 12KB [2][1536]
    float* out   = (float*)d_out;

    // weight prep
    transpose_cast<<<dim3(32, 8, 2), 256, 0, stream>>>(in_proj_w, iprT, 512, 2048, 512*2048, 512*2048);
    transpose_cast<<<dim3(8, 16, 2), 256, 0, stream>>>(out_w_m, outT, 1024, 512, 1024*512, 1024*512);
    transpose_cast<<<dim3(8, 8, 2), 256, 0, stream>>>(wq, qkvT,          512, 512, 512*512, 1536*512);
    transpose_cast<<<dim3(8, 8, 2), 256, 0, stream>>>(wk, qkvT + 512*512, 512, 512, 512*512, 1536*512);
    transpose_cast<<<dim3(8, 8, 2), 256, 0, stream>>>(wv, qkvT + 1024*512, 512, 512, 512*512, 1536*512);
    transpose_cast<<<dim3(8, 8, 2), 256, 0, stream>>>(wo, oT, 512, 512, 512*512, 512*512);
    transpose_cast<<<dim3(1, 16, 2), 256, 0, stream>>>(x_proj_w, xprT, 1024, 64, 1024*64, 1024*64);
    dtw_transpose<<<512, 256, 0, stream>>>(dt_w, dtwT);
    pack_bias<<<12, 256, 0, stream>>>(bq, bk, bv, biasP);

    embed_kernel<<<ROWS, 256, 0, stream>>>(x_dec, x_mark, token_w, temp_w, x, xbf);

    for (int i = 0; i < 2; ++i) {
        // xz = x @ in_proj   (8192 x 2048 x 512), bf16 out
        gemm_bf16<1,0><<<1024, 256, 0, stream>>>(xbf, 512, iprT + (size_t)i*2048*512, 512,
                                                 nullptr, xzb, 2048, 16, 2048, 512, nullptr);
        conv_silu_kernel<<<(ROWS*128)/256, 256, 0, stream>>>(xzb, conv_w + i*D_INNER*D_CONV,
                                                             conv_b + i*D_INNER, ucb);
        // dbc = uc @ x_proj  (8192 x 64 x 1024), f32 + padded dt slice bf16
        xproj_kernel<<<ROWS/64, 256, 0, stream>>>(ucb, xprT + (size_t)i*64*1024, dbc, dtb);
        // delta = softplus(dt @ dt_w + dt_b)  (8192 x 1024 x 64pad), bf16 out
        gemm_bf16<1,1><<<512, 256, 0, stream>>>(dtb, 64, dtwT + (size_t)i*1024*64, 64,
                                                dt_b + i*D_INNER, delta, 1024, 8, 1024, 64, nullptr);
        // chunked scan (3 passes) + fused skip/gate
        scan_part1<<<dim3(32, NCHUNK), 256, 0, stream>>>(delta, ucb, dbc, A_log + i*D_INNER*D_STATE,
                                                         hend, aprod);
        scan_part2<<<(ROWS*D_STATE)/256, 256, 0, stream>>>(hend, aprod);
        scan_part3<<<dim3(32, NCHUNK), 256, 0, stream>>>(delta, ucb, dbc, A_log + i*D_INNER*D_STATE,
                                                         hend, xzb, D_skip + i*D_INNER, ysb);
        // tmp = ys @ out_w   (8192 x 512 x 1024), bf16 out
        gemm_bf16<1,0><<<256, 256, 0, stream>>>(ysb, 1024, outT + (size_t)i*512*1024, 1024,
                                                nullptr, tmp, 512, 4, 512, 1024, nullptr);
        ln_kernel<<<ROWS/4, 256, 0, stream>>>(x, tmp, ln1_g + i*512, ln1_b + i*512, xbf);
        // fused qkv (8192 x 1536 x 512): q,k -> qk buffer; v -> vt transposed
        gemm_bf16<3,0><<<768, 256, 0, stream>>>(xbf, 512, qkvT + (size_t)i*1536*512, 512,
                                                biasP + i*1536, qk, 1024, 12, 1536, 512, vtb);
        attn_mfma<<<dim3(Ldim/64, N_HEADS, Bdim), 256, 0, stream>>>(qk, vtb, obf);
        // tmp = o @ wo + bo  (8192 x 512 x 512), bf16 out
        gemm_bf16<1,0><<<256, 256, 0, stream>>>(obf, 512, oT + (size_t)i*512*512, 512,
                                                bo + i*512, tmp, 512, 4, 512, 512, nullptr);
        ln_kernel<<<ROWS/4, 256, 0, stream>>>(x, tmp, ln2_g + i*512, ln2_b + i*512, xbf);
    }
    proj_kernel<<<ROWS/4, 256, 0, stream>>>(x, proj_w, proj_b, out);
}

// Round 7
// 813.800 us; speedup vs baseline: 7.5774x; 1.1055x over previous
//
#include <hip/hip_runtime.h>
#include <math.h>

#define Bdim 8
#define Ldim 1024
#define DEC_IN 7
#define D_MODEL 512
#define MARK 4
#define D_INNER 1024
#define D_STATE 16
#define D_CONV 4
#define DT_RANK 32
#define N_HEADS 8
#define DH 64
#define ROWS (Bdim*Ldim)   // 8192
#define MB (1ull<<20)
#define NCHUNK 32
#define CLEN 32            // Ldim / NCHUNK

typedef unsigned short u16;
typedef unsigned int u32;
typedef __attribute__((ext_vector_type(8))) short bf16x8;
typedef __attribute__((ext_vector_type(4))) float f32x4;
typedef __attribute__((ext_vector_type(4))) unsigned short u16x4;

__device__ inline float b2f(u16 u) {
    union { u32 i; float f; } c; c.i = ((u32)u) << 16; return c.f;
}
__device__ inline u16 f2b(float f) {
    union { float f; u32 u; } c; c.f = f;
    u32 u = c.u;
    u32 r = (u + 0x7fffu + ((u >> 16) & 1u)) >> 16;
    return (u16)r;
}
__device__ inline void gload16(const void* g, void* l) {
    __builtin_amdgcn_global_load_lds((const __attribute__((address_space(1))) void*)g,
                                     (__attribute__((address_space(3))) void*)l, 16, 0, 0);
}

// ---------------- embed: token circular conv3 + pos embed + mark proj (dual f32/bf16 out) ----------------
__global__ void embed_kernel(const float* __restrict__ xd, const float* __restrict__ xmark,
                             const float* __restrict__ token_w, const float* __restrict__ temp_w,
                             float* __restrict__ x, u16* __restrict__ xbf) {
    int bt = blockIdx.x;            // 0..8191
    int b = bt >> 10, t = bt & 1023;
    __shared__ float xr[3][DEC_IN];
    __shared__ float mk[MARK];
    if (threadIdx.x < 3*DEC_IN) {
        int k = threadIdx.x / DEC_IN, c = threadIdx.x % DEC_IN;
        int tt = (t + k - 1 + Ldim) % Ldim;
        xr[k][c] = xd[((size_t)b*Ldim + tt)*DEC_IN + c];
    }
    if (threadIdx.x < MARK) mk[threadIdx.x] = xmark[((size_t)b*Ldim + t)*MARK + threadIdx.x];
    __syncthreads();
    for (int dd = threadIdx.x; dd < D_MODEL; dd += 256) {
        float acc = 0.f;
        #pragma unroll
        for (int k = 0; k < 3; ++k)
            #pragma unroll
            for (int c = 0; c < DEC_IN; ++c)
                acc += xr[k][c] * token_w[(k*DEC_IN + c)*D_MODEL + dd];
        int i2 = dd & ~1;
        float freq = expf(-(float)i2 * (logf(10000.f) / (float)D_MODEL));
        float ang = (float)t * freq;
        acc += (dd & 1) ? cosf(ang) : sinf(ang);
        #pragma unroll
        for (int m = 0; m < MARK; ++m) acc += mk[m] * temp_w[m*D_MODEL + dd];
        x[(size_t)bt*D_MODEL + dd] = acc;
        xbf[(size_t)bt*D_MODEL + dd] = f2b(acc);
    }
}

// ---------------- weight transpose + cast: W[K][N] f32 -> Wt[N][K] bf16 (K,N mult of 64) ----------------
__global__ __launch_bounds__(256) void transpose_cast(const float* __restrict__ W, u16* __restrict__ Wt,
                                                      int K, int N, int srcZ, int dstZ) {
    const float* Wz = W + (size_t)blockIdx.z * srcZ;
    u16* Wtz = Wt + (size_t)blockIdx.z * dstZ;
    __shared__ u16 tile[64][72];
    int k0 = blockIdx.y*64, n0 = blockIdx.x*64;
    int tid = threadIdx.x;
    #pragma unroll
    for (int it = 0; it < 16; ++it) {
        int idx = it*256 + tid; int kr = idx>>6, nc = idx&63;
        tile[kr][nc] = f2b(Wz[(size_t)(k0+kr)*N + n0 + nc]);
    }
    __syncthreads();
    #pragma unroll
    for (int it = 0; it < 2; ++it) {
        int idx = it*256 + tid; int nr = idx>>3, slot = idx&7;
        bf16x8 v;
        #pragma unroll
        for (int j = 0; j < 8; ++j) ((u16*)&v)[j] = tile[slot*8+j][nr];
        *(bf16x8*)(Wtz + (size_t)(n0+nr)*K + k0 + slot*8) = v;
    }
}

// ---------------- dt_w transpose+pad: [2][32][1024] f32 -> [2][1024][64] bf16 (zero k>=32) ----------------
__global__ void dtw_transpose(const float* __restrict__ dt_w, u16* __restrict__ dtwT) {
    int idx = blockIdx.x*256 + threadIdx.x;   // 0..131071
    int z = idx >> 16, rem = idx & 65535;
    int n = rem >> 6, k = rem & 63;
    dtwT[idx] = (k < 32) ? f2b(dt_w[(size_t)z*32768 + k*1024 + n]) : (u16)0;
}

// ---------------- pack q/k/v bias: [2][1536] ----------------
__global__ void pack_bias(const float* __restrict__ bq, const float* __restrict__ bk,
                          const float* __restrict__ bv, float* __restrict__ dst) {
    int idx = blockIdx.x*256 + threadIdx.x;   // 0..3071
    int layer = idx / 1536, c = idx % 1536;
    const float* src = (c < 512) ? bq : (c < 1024) ? bk : bv;
    dst[idx] = src[layer*512 + (c & 511)];
}

// ---------------- bf16 MFMA GEMM: C = A@Bt^T (+bias)(+act) ----------------
// 128x128 tile, BK=64, global_load_lds staging with PRE-SWIZZLED global source
// (rule 21: linear LDS dest + inverse-swizzled source + XOR'd ds_read).
// OUTMODE: 1 = bf16 out, 3 = qkv split (col<1024 -> qk, col>=1024 -> vt transposed)
// ACT: 0 = none, 1 = softplus. Grid is 1D (nwg % 8 == 0), XCD-chunked swizzle.
template<int OUTMODE, int ACT>
__global__ __launch_bounds__(256) void gemm_bf16(const u16* __restrict__ A, int lda,
                                                 const u16* __restrict__ Bt, int ldb,
                                                 const float* __restrict__ bias, void* __restrict__ Cp,
                                                 int ldc, int gridX, int N, int K,
                                                 u16* __restrict__ vt) {
    __shared__ u16 As[128*64];
    __shared__ u16 Bs[128*64];
    int tid = threadIdx.x;
    int nwg = gridDim.x, q8 = nwg >> 3;
    int bid = blockIdx.x;
    int wg = (bid & 7)*q8 + (bid >> 3);          // XCD-chunked swizzle
    int bx = wg % gridX, by = wg / gridX;
    int bm = by*128, bn = bx*128;
    int lane = tid & 63, wv = tid >> 6;
    int rm = (wv & 1)*64, cn = (wv >> 1)*64;
    int l15 = lane & 15, g = lane >> 4;
    int lrow = lane >> 3;
    int lcol = ((lane & 7) ^ lrow) * 8;          // pre-swizzled source column

    f32x4 acc[4][4] = {};

    for (int k0 = 0; k0 < K; k0 += 64) {
        __syncthreads();
        #pragma unroll
        for (int it = 0; it < 4; ++it) {
            int r0 = wv*32 + it*8;
            gload16(A  + (size_t)(bm + r0 + lrow)*lda + k0 + lcol, As + r0*64);
            gload16(Bt + (size_t)(bn + r0 + lrow)*ldb + k0 + lcol, Bs + r0*64);
        }
        __syncthreads();
        #pragma unroll
        for (int ks = 0; ks < 2; ++ks) {
            bf16x8 af[4], bfr[4];
            #pragma unroll
            for (int m = 0; m < 4; ++m) {
                int row = rm + m*16 + l15;
                af[m]  = *(const bf16x8*)(As + row*64 + (((ks*4+g) ^ (row&7))*8));
                int col = cn + m*16 + l15;
                bfr[m] = *(const bf16x8*)(Bs + col*64 + (((ks*4+g) ^ (col&7))*8));
            }
            #pragma unroll
            for (int m = 0; m < 4; ++m)
                #pragma unroll
                for (int n = 0; n < 4; ++n)
                    acc[m][n] = __builtin_amdgcn_mfma_f32_16x16x32_bf16(af[m], bfr[n], acc[m][n], 0, 0, 0);
        }
    }

    float bv4[4];
    #pragma unroll
    for (int n = 0; n < 4; ++n) bv4[n] = bias ? bias[bn + cn + n*16 + l15] : 0.f;

    #pragma unroll
    for (int m = 0; m < 4; ++m) {
        #pragma unroll
        for (int n = 0; n < 4; ++n) {
            int col = bn + cn + n*16 + l15;
            #pragma unroll
            for (int r = 0; r < 4; ++r) {
                int row = bm + rm + m*16 + g*4 + r;
                float v = acc[m][n][r] + bv4[n];
                if (ACT == 1) v = (v > 20.f) ? v : log1pf(__expf(v));
                if (OUTMODE == 1) {
                    ((u16*)Cp)[(size_t)row*ldc + col] = f2b(v);
                } else {   // OUTMODE 3: qkv split
                    int b = row >> 10, t = row & 1023;
                    if (col < 1024) ((u16*)Cp)[(size_t)row*ldc + col] = f2b(v);
                    else vt[((size_t)(b*D_MODEL) + (col - 1024))*Ldim + t] = f2b(v);
                }
            }
        }
    }
}

// ---------------- x_proj MFMA: dbc = ucb @ xprT^T (8192x64x1024), f32 dbc + bf16 dtb (64-wide, padded) ----------------
__global__ __launch_bounds__(256) void xproj_kernel(const u16* __restrict__ ucb, const u16* __restrict__ xprT,
                                                    float* __restrict__ dbc, u16* __restrict__ dtb) {
    __shared__ u16 As[64*64];
    __shared__ u16 Bs[64*64];
    int tid = threadIdx.x, lane = tid & 63, wv = tid >> 6;
    int l15 = lane & 15, g = lane >> 4;
    int bm = blockIdx.x*64;
    f32x4 acc[4] = {};
    for (int k0 = 0; k0 < 1024; k0 += 64) {
        __syncthreads();
        #pragma unroll
        for (int it = 0; it < 2; ++it) {
            int idx = it*256 + tid; int row = idx >> 3, slot = idx & 7;
            bf16x8 av = *(const bf16x8*)(ucb + (size_t)(bm+row)*1024 + k0 + slot*8);
            *(bf16x8*)((char*)As + row*128 + ((slot ^ (row&7)) << 4)) = av;
            bf16x8 bv = *(const bf16x8*)(xprT + (size_t)row*1024 + k0 + slot*8);
            *(bf16x8*)((char*)Bs + row*128 + ((slot ^ (row&7)) << 4)) = bv;
        }
        __syncthreads();
        #pragma unroll
        for (int ks = 0; ks < 2; ++ks) {
            int arow = wv*16 + l15;
            bf16x8 af = *(const bf16x8*)((const char*)As + arow*128 + (((ks*4+g) ^ (arow&7)) << 4));
            #pragma unroll
            for (int n = 0; n < 4; ++n) {
                int col = n*16 + l15;
                bf16x8 bfr = *(const bf16x8*)((const char*)Bs + col*128 + (((ks*4+g) ^ (col&7)) << 4));
                acc[n] = __builtin_amdgcn_mfma_f32_16x16x32_bf16(af, bfr, acc[n], 0, 0, 0);
            }
        }
    }
    #pragma unroll
    for (int n = 0; n < 4; ++n) {
        int col = n*16 + l15;
        #pragma unroll
        for (int r = 0; r < 4; ++r) {
            int row = bm + wv*16 + g*4 + r;
            float v = acc[n][r];
            dbc[(size_t)row*64 + col] = v;
            dtb[(size_t)row*64 + col] = (col < 32) ? f2b(v) : (u16)0;
        }
    }
}

// ---------------- final proj: out = x @ proj_w + proj_b (wave per row, N=7) ----------------
__global__ __launch_bounds__(256) void proj_kernel(const float* __restrict__ x, const float* __restrict__ w,
                                                   const float* __restrict__ pb, float* __restrict__ out) {
    int row = blockIdx.x*4 + (threadIdx.x >> 6);
    int lane = threadIdx.x & 63;
    const float* xr = x + (size_t)row*D_MODEL + lane*8;
    float xv[8];
    #pragma unroll
    for (int j = 0; j < 8; ++j) xv[j] = xr[j];
    const float* wr = w + lane*56;
    float acc[7] = {0,0,0,0,0,0,0};
    #pragma unroll
    for (int j = 0; j < 8; ++j)
        #pragma unroll
        for (int c = 0; c < 7; ++c) acc[c] = fmaf(xv[j], wr[j*7 + c], acc[c]);
    #pragma unroll
    for (int c = 0; c < 7; ++c) {
        #pragma unroll
        for (int off = 32; off; off >>= 1) acc[c] += __shfl_xor(acc[c], off);
    }
    if (lane < 7) out[(size_t)row*7 + lane] = acc[lane] + pb[lane];
}

// ---------------- causal conv1d (k=4) + SiLU, vectorized weights ----------------
__global__ void conv_silu_kernel(const u16* __restrict__ xz, const float* __restrict__ conv_w,
                                 const float* __restrict__ conv_b, u16* __restrict__ ucb) {
    int idx = blockIdx.x*256 + threadIdx.x;   // over ROWS*128
    int d8 = idx & 127, bt = idx >> 7;
    int t = bt & 1023, b = bt >> 10;
    int d0 = d8*8;
    float4 cb0 = *(const float4*)(conv_b + d0);
    float4 cb1 = *(const float4*)(conv_b + d0 + 4);
    float acc[8] = {cb0.x,cb0.y,cb0.z,cb0.w, cb1.x,cb1.y,cb1.z,cb1.w};
    float w[8][4];
    #pragma unroll
    for (int j = 0; j < 8; ++j) *(float4*)&w[j][0] = *(const float4*)(conv_w + (d0+j)*4);
    #pragma unroll
    for (int k = 0; k < 4; ++k) {
        int tt = t + k - 3;
        if (tt >= 0) {
            bf16x8 v = *(const bf16x8*)(xz + ((size_t)(b*Ldim + tt))*2048 + d0);
            #pragma unroll
            for (int j = 0; j < 8; ++j)
                acc[j] = fmaf(b2f(((u16*)&v)[j]), w[j][k], acc[j]);
        }
    }
    bf16x8 o;
    #pragma unroll
    for (int j = 0; j < 8; ++j) {
        float s = acc[j] / (1.f + __expf(-acc[j]));
        ((u16*)&o)[j] = f2b(s);
    }
    *(bf16x8*)(ucb + (size_t)bt*1024 + d0) = o;
}

// ---------------- chunked selective scan, pass 1 ----------------
__global__ __launch_bounds__(256) void scan_part1(const u16* __restrict__ delta,
                                                  const u16* __restrict__ ucb,
                                                  const float* __restrict__ dbc,
                                                  const float* __restrict__ A_log,
                                                  float* __restrict__ hend,
                                                  float* __restrict__ aprod) {
    int c = blockIdx.y;
    int bd = blockIdx.x*256 + threadIdx.x;   // 0..8191
    int d = bd & 1023, b = bd >> 10;
    float A[D_STATE], h[D_STATE], ap[D_STATE];
    #pragma unroll
    for (int s = 0; s < D_STATE; ++s) { A[s] = -__expf(A_log[d*D_STATE + s]); h[s] = 0.f; ap[s] = 1.f; }
    const u16*   dptr = delta + (size_t)b*Ldim*D_INNER + d;
    const u16*   uptr = ucb   + (size_t)b*Ldim*D_INNER + d;
    const float* bc   = dbc   + (size_t)b*Ldim*64;
    for (int tt = 0; tt < CLEN; ++tt) {
        int t = c*CLEN + tt;
        float dl = b2f(dptr[(size_t)t*D_INNER]);
        float ut = b2f(uptr[(size_t)t*D_INNER]);
        float du = dl * ut;
        float4 b0 = *(const float4*)(bc + t*64 + 32);
        float4 b1 = *(const float4*)(bc + t*64 + 36);
        float4 b2 = *(const float4*)(bc + t*64 + 40);
        float4 b3 = *(const float4*)(bc + t*64 + 44);
        float Bv[16] = {b0.x,b0.y,b0.z,b0.w, b1.x,b1.y,b1.z,b1.w,
                        b2.x,b2.y,b2.z,b2.w, b3.x,b3.y,b3.z,b3.w};
        #pragma unroll
        for (int s = 0; s < D_STATE; ++s) {
            float e = __expf(dl * A[s]);
            h[s] = fmaf(e, h[s], du * Bv[s]);
            ap[s] *= e;
        }
    }
    size_t o = ((size_t)c*ROWS + bd)*D_STATE;
    #pragma unroll
    for (int q = 0; q < 4; ++q) {
        *(float4*)(hend  + o + q*4) = make_float4(h[q*4],  h[q*4+1],  h[q*4+2],  h[q*4+3]);
        *(float4*)(aprod + o + q*4) = make_float4(ap[q*4], ap[q*4+1], ap[q*4+2], ap[q*4+3]);
    }
}

// ---------------- pass 2: combine chunk states ----------------
__global__ __launch_bounds__(256) void scan_part2(float* __restrict__ hend,
                                                  const float* __restrict__ aprod) {
    int idx = blockIdx.x*256 + threadIdx.x;  // 0..131071
    float hin = 0.f;
    #pragma unroll
    for (int c = 0; c < NCHUNK; ++c) {
        size_t o = (size_t)c*ROWS*D_STATE + idx;
        float he = hend[o], ap = aprod[o];
        hend[o] = hin;
        hin = fmaf(ap, hin, he);
    }
}

// ---------------- pass 3: replay from h_in, fused skip + silu(z) gate, bf16 out ----------------
__global__ __launch_bounds__(256) void scan_part3(const u16* __restrict__ delta,
                                                  const u16* __restrict__ ucb,
                                                  const float* __restrict__ dbc,
                                                  const float* __restrict__ A_log,
                                                  const float* __restrict__ hend,
                                                  const u16* __restrict__ xz,
                                                  const float* __restrict__ Dskip,
                                                  u16* __restrict__ ysb) {
    int c = blockIdx.y;
    int bd = blockIdx.x*256 + threadIdx.x;
    int d = bd & 1023, b = bd >> 10;
    float A[D_STATE], h[D_STATE];
    size_t o = ((size_t)c*ROWS + bd)*D_STATE;
    #pragma unroll
    for (int s = 0; s < D_STATE; ++s) {
        A[s] = -__expf(A_log[d*D_STATE + s]);
        h[s] = hend[o + s];
    }
    float Dk = Dskip[d];
    const u16*   dptr = delta + (size_t)b*Ldim*D_INNER + d;
    const u16*   uptr = ucb   + (size_t)b*Ldim*D_INNER + d;
    const float* bc   = dbc   + (size_t)b*Ldim*64;
    const u16*   zp   = xz    + (size_t)b*Ldim*2048 + 1024 + d;
    u16* yp = ysb + (size_t)b*Ldim*D_INNER + d;
    for (int tt = 0; tt < CLEN; ++tt) {
        int t = c*CLEN + tt;
        float dl = b2f(dptr[(size_t)t*D_INNER]);
        float ut = b2f(uptr[(size_t)t*D_INNER]);
        float du = dl * ut;
        float4 b0 = *(const float4*)(bc + t*64 + 32);
        float4 b1 = *(const float4*)(bc + t*64 + 36);
        float4 b2 = *(const float4*)(bc + t*64 + 40);
        float4 b3 = *(const float4*)(bc + t*64 + 44);
        float4 c0 = *(const float4*)(bc + t*64 + 48);
        float4 c1 = *(const float4*)(bc + t*64 + 52);
        float4 c2 = *(const float4*)(bc + t*64 + 56);
        float4 c3 = *(const float4*)(bc + t*64 + 60);
        float Bv[16] = {b0.x,b0.y,b0.z,b0.w, b1.x,b1.y,b1.z,b1.w,
                        b2.x,b2.y,b2.z,b2.w, b3.x,b3.y,b3.z,b3.w};
        float Cv[16] = {c0.x,c0.y,c0.z,c0.w, c1.x,c1.y,c1.z,c1.w,
                        c2.x,c2.y,c2.z,c2.w, c3.x,c3.y,c3.z,c3.w};
        float y = 0.f;
        #pragma unroll
        for (int s = 0; s < D_STATE; ++s) {
            float e = __expf(dl * A[s]);
            h[s] = fmaf(e, h[s], du * Bv[s]);
            y = fmaf(h[s], Cv[s], y);
        }
        float z = b2f(zp[(size_t)t*2048]);
        float yy = fmaf(ut, Dk, y);
        yp[(size_t)t*D_INNER] = f2b(yy * (z / (1.f + __expf(-z))));
    }
}

// ---------------- fused residual + LayerNorm (tmp bf16), dual f32/bf16 out ----------------
__global__ __launch_bounds__(256) void ln_kernel(float* __restrict__ x, const u16* __restrict__ t,
                                                 const float* __restrict__ g, const float* __restrict__ bta,
                                                 u16* __restrict__ xbf) {
    int row = blockIdx.x * 4 + (threadIdx.x >> 6);
    int lane = threadIdx.x & 63;
    const float* xr = x + (size_t)row*D_MODEL;
    const u16*   tr = t + (size_t)row*D_MODEL;
    float v[8];
    float sum = 0.f;
    #pragma unroll
    for (int j = 0; j < 8; ++j) { v[j] = xr[lane + j*64] + b2f(tr[lane + j*64]); sum += v[j]; }
    #pragma unroll
    for (int off = 32; off; off >>= 1) sum += __shfl_xor(sum, off);
    float mu = sum * (1.f/512.f);
    float vs = 0.f;
    #pragma unroll
    for (int j = 0; j < 8; ++j) { float dm = v[j] - mu; vs += dm*dm; }
    #pragma unroll
    for (int off = 32; off; off >>= 1) vs += __shfl_xor(vs, off);
    float inv = rsqrtf(vs * (1.f/512.f) + 1e-5f);
    #pragma unroll
    for (int j = 0; j < 8; ++j) {
        int c = lane + j*64;
        float o = (v[j] - mu) * inv * g[c] + bta[c];
        x[(size_t)row*D_MODEL + c] = o;
        xbf[(size_t)row*D_MODEL + c] = f2b(o);
    }
}

// ---------------- MFMA flash attention: S^T = mfma(K,Q), O^T = mfma(V^T, P^T) ----------------
// q,k packed in one buffer qk[bt][1024]: q cols 0..511, k cols 512..1023.
__global__ __launch_bounds__(256) void attn_mfma(const u16* __restrict__ qk,
                                                 const u16* __restrict__ vt, u16* __restrict__ ob) {
    int bx = blockIdx.x, h = blockIdx.y, b = blockIdx.z;
    int tid = threadIdx.x, lane = tid & 63, w = tid >> 6;
    int l15 = lane & 15, g = lane >> 4;
    __shared__ u16 Ks[32*64];       // [key][dh], 128B rows, XOR swizzled
    __shared__ u16 Vs[64*40];       // [dh][key], 80B rows
    __shared__ u16 Ps[4][16*40];    // per-wave P [q][key], 80B rows
    int qbase = bx*64;
    int qrow = qbase + w*16 + l15;

    const u16* qptr = qk + ((size_t)(b*Ldim + qrow))*1024 + h*DH + g*8;
    bf16x8 qf[2];
    qf[0] = *(const bf16x8*)(qptr);
    qf[1] = *(const bf16x8*)(qptr + 32);

    f32x4 o_acc[4] = {};
    float m_run = -INFINITY, l_run = 0.f;
    int ntiles = bx*2 + 2;

    for (int kt = 0; kt < ntiles; ++kt) {
        __syncthreads();
        {   // stage K tile: 32 keys x 64 dh
            int row = tid >> 3, slot = tid & 7;
            bf16x8 v = *(const bf16x8*)(qk + ((size_t)(b*Ldim + kt*32 + row))*1024 + 512 + h*DH + slot*8);
            *(bf16x8*)((char*)Ks + row*128 + ((slot ^ (row&7)) << 4)) = v;
        }
        {   // stage V^T tile: 64 dh x 32 keys
            int row = tid >> 2, slot = tid & 3;
            bf16x8 v = *(const bf16x8*)(vt + ((size_t)(b*D_MODEL + h*DH + row))*Ldim + kt*32 + slot*8);
            *(bf16x8*)((char*)Vs + row*80 + slot*16) = v;
        }
        __syncthreads();

        f32x4 sf[2];
        #pragma unroll
        for (int f = 0; f < 2; ++f) {
            f32x4 a = {0.f, 0.f, 0.f, 0.f};
            #pragma unroll
            for (int ks = 0; ks < 2; ++ks) {
                int row = f*16 + l15;
                bf16x8 kf = *(const bf16x8*)((const char*)Ks + row*128 + (((ks*4+g) ^ (row&7)) << 4));
                a = __builtin_amdgcn_mfma_f32_16x16x32_bf16(kf, qf[ks], a, 0, 0, 0);
            }
            sf[f] = a;
        }

        float pmax = -INFINITY;
        #pragma unroll
        for (int f = 0; f < 2; ++f)
            #pragma unroll
            for (int r = 0; r < 4; ++r) {
                int key = kt*32 + f*16 + g*4 + r;
                float sv = (key <= qrow) ? sf[f][r]*0.125f : -INFINITY;
                sf[f][r] = sv;
                pmax = fmaxf(pmax, sv);
            }
        pmax = fmaxf(pmax, __shfl_xor(pmax, 16));
        pmax = fmaxf(pmax, __shfl_xor(pmax, 32));
        float mnew = fmaxf(m_run, pmax);
        float corr = __expf(m_run - mnew);

        float ps = 0.f;
        #pragma unroll
        for (int f = 0; f < 2; ++f) {
            float p0 = __expf(sf[f][0] - mnew), p1 = __expf(sf[f][1] - mnew);
            float p2 = __expf(sf[f][2] - mnew), p3 = __expf(sf[f][3] - mnew);
            ps += p0 + p1 + p2 + p3;
            u16x4 pk; pk.x = f2b(p0); pk.y = f2b(p1); pk.z = f2b(p2); pk.w = f2b(p3);
            *(u16x4*)((char*)&Ps[w][0] + l15*80 + f*32 + g*8) = pk;
        }
        ps += __shfl_xor(ps, 16);
        ps += __shfl_xor(ps, 32);
        l_run = l_run * corr + ps;
        m_run = mnew;
        #pragma unroll
        for (int t = 0; t < 4; ++t) o_acc[t] *= corr;

        bf16x8 pf = *(const bf16x8*)((const char*)&Ps[w][0] + l15*80 + g*16);
        #pragma unroll
        for (int t = 0; t < 4; ++t) {
            int row = t*16 + l15;
            bf16x8 vf = *(const bf16x8*)((const char*)Vs + row*80 + g*16);
            o_acc[t] = __builtin_amdgcn_mfma_f32_16x16x32_bf16(vf, pf, o_acc[t], 0, 0, 0);
        }
    }

    float invl = 1.f / l_run;
    #pragma unroll
    for (int t = 0; t < 4; ++t) {
        u16x4 o4;
        o4.x = f2b(o_acc[t][0]*invl); o4.y = f2b(o_acc[t][1]*invl);
        o4.z = f2b(o_acc[t][2]*invl); o4.w = f2b(o_acc[t][3]*invl);
        *(u16x4*)(ob + ((size_t)(b*Ldim + qrow))*D_MODEL + h*DH + t*16 + g*4) = o4;
    }
}

extern "C" void kernel_launch(void* const* d_in, const int* in_sizes, int n_in,
                              void* d_out, int out_size, void* d_ws, size_t ws_size,
                              hipStream_t stream) {
    const float* x_dec   = (const float*)d_in[0];
    const float* x_mark  = (const float*)d_in[1];
    const float* token_w = (const float*)d_in[2];
    const float* temp_w  = (const float*)d_in[3];
    const float* in_proj_w = (const float*)d_in[4];
    const float* conv_w  = (const float*)d_in[5];
    const float* conv_b  = (const float*)d_in[6];
    const float* x_proj_w = (const float*)d_in[7];
    const float* dt_w    = (const float*)d_in[8];
    const float* dt_b    = (const float*)d_in[9];
    const float* A_log   = (const float*)d_in[10];
    const float* D_skip  = (const float*)d_in[11];
    const float* out_w_m = (const float*)d_in[12];
    const float* wq = (const float*)d_in[13];
    const float* bq = (const float*)d_in[14];
    const float* wk = (const float*)d_in[15];
    const float* bk = (const float*)d_in[16];
    const float* wv = (const float*)d_in[17];
    const float* bv = (const float*)d_in[18];
    const float* wo = (const float*)d_in[19];
    const float* bo = (const float*)d_in[20];
    const float* ln1_g = (const float*)d_in[21];
    const float* ln1_b = (const float*)d_in[22];
    const float* ln2_g = (const float*)d_in[23];
    const float* ln2_b = (const float*)d_in[24];
    const float* proj_w = (const float*)d_in[25];
    const float* proj_b = (const float*)d_in[26];

    if (ws_size < 160*MB) return;

    char* wsb = (char*)d_ws;
    float* x     = (float*)(wsb + 0);          // 16MB
    u16*   xbf   = (u16*)(wsb + 16*MB);        // 8MB
    u16*   xzb   = (u16*)(wsb + 24*MB);        // 32MB (aliased by qk/obf after scan)
    u16*   qk    = (u16*)(wsb + 24*MB);        // 16MB  [8192][1024]
    u16*   obf   = (u16*)(wsb + 40*MB);        // 8MB
    u16*   vtb   = (u16*)(wsb + 56*MB);        // 8MB
    u16*   ucb   = (u16*)(wsb + 64*MB);        // 16MB
    float* hend  = (float*)(wsb + 80*MB);      // 16MB (32 chunks)
    float* aprod = (float*)(wsb + 96*MB);      // 16MB
    float* dbc   = (float*)(wsb + 112*MB);     // 2MB
    u16*   dtb   = (u16*)(wsb + 114*MB);       // 1MB  [8192][64] padded
    u16*   delta = (u16*)(wsb + 115*MB);       // 16MB bf16
    u16*   tmp   = delta;                      // alias: delta dead when tmp used
    u16*   ysb   = (u16*)(wsb + 131*MB);       // 16MB
    u16*   iprT  = (u16*)(wsb + 147*MB);       // 4MB
    u16*   outT  = (u16*)(wsb + 151*MB);       // 2MB
    u16*   qkvT  = (u16*)(wsb + 153*MB);       // 3MB  [2][1536][512]
    u16*   oT    = (u16*)(wsb + 156*MB);       // 1MB
    u16*   xprT  = (u16*)(wsb + 157*MB);       // 256KB
    u16*   dtwT  = (u16*)(wsb + 158*MB);       // 256KB [2][1024][64] padded
    float* biasP = (float*)(wsb + 159*MB);     // 12KB [2][1536]
    float* out   = (float*)d_out;

    // weight prep
    transpose_cast<<<dim3(32, 8, 2), 256, 0, stream>>>(in_proj_w, iprT, 512, 2048, 512*2048, 512*2048);
    transpose_cast<<<dim3(8, 16, 2), 256, 0, stream>>>(out_w_m, outT, 1024, 512, 1024*512, 1024*512);
    transpose_cast<<<dim3(8, 8, 2), 256, 0, stream>>>(wq, qkvT,          512, 512, 512*512, 1536*512);
    transpose_cast<<<dim3(8, 8, 2), 256, 0, stream>>>(wk, qkvT + 512*512, 512, 512, 512*512, 1536*512);
    transpose_cast<<<dim3(8, 8, 2), 256, 0, stream>>>(wv, qkvT + 1024*512, 512, 512, 512*512, 1536*512);
    transpose_cast<<<dim3(8, 8, 2), 256, 0, stream>>>(wo, oT, 512, 512, 512*512, 512*512);
    transpose_cast<<<dim3(1, 16, 2), 256, 0, stream>>>(x_proj_w, xprT, 1024, 64, 1024*64, 1024*64);
    dtw_transpose<<<512, 256, 0, stream>>>(dt_w, dtwT);
    pack_bias<<<12, 256, 0, stream>>>(bq, bk, bv, biasP);

    embed_kernel<<<ROWS, 256, 0, stream>>>(x_dec, x_mark, token_w, temp_w, x, xbf);

    for (int i = 0; i < 2; ++i) {
        // xz = x @ in_proj   (8192 x 2048 x 512), bf16 out
        gemm_bf16<1,0><<<1024, 256, 0, stream>>>(xbf, 512, iprT + (size_t)i*2048*512, 512,
                                                 nullptr, xzb, 2048, 16, 2048, 512, nullptr);
        conv_silu_kernel<<<(ROWS*128)/256, 256, 0, stream>>>(xzb, conv_w + i*D_INNER*D_CONV,
                                                             conv_b + i*D_INNER, ucb);
        // dbc = uc @ x_proj  (8192 x 64 x 1024), f32 + padded dt slice bf16
        xproj_kernel<<<ROWS/64, 256, 0, stream>>>(ucb, xprT + (size_t)i*64*1024, dbc, dtb);
        // delta = softplus(dt @ dt_w + dt_b)  (8192 x 1024 x 64pad), bf16 out
        gemm_bf16<1,1><<<512, 256, 0, stream>>>(dtb, 64, dtwT + (size_t)i*1024*64, 64,
                                                dt_b + i*D_INNER, delta, 1024, 8, 1024, 64, nullptr);
        // chunked scan (3 passes) + fused skip/gate
        scan_part1<<<dim3(32, NCHUNK), 256, 0, stream>>>(delta, ucb, dbc, A_log + i*D_INNER*D_STATE,
                                                         hend, aprod);
        scan_part2<<<(ROWS*D_STATE)/256, 256, 0, stream>>>(hend, aprod);
        scan_part3<<<dim3(32, NCHUNK), 256, 0, stream>>>(delta, ucb, dbc, A_log + i*D_INNER*D_STATE,
                                                         hend, xzb, D_skip + i*D_INNER, ysb);
        // tmp = ys @ out_w   (8192 x 512 x 1024), bf16 out
        gemm_bf16<1,0><<<256, 256, 0, stream>>>(ysb, 1024, outT + (size_t)i*512*1024, 1024,
                                                nullptr, tmp, 512, 4, 512, 1024, nullptr);
        ln_kernel<<<ROWS/4, 256, 0, stream>>>(x, tmp, ln1_g + i*512, ln1_b + i*512, xbf);
        // fused qkv (8192 x 1536 x 512): q,k -> qk buffer; v -> vt transposed
        gemm_bf16<3,0><<<768, 256, 0, stream>>>(xbf, 512, qkvT + (size_t)i*1536*512, 512,
                                                biasP + i*1536, qk, 1024, 12, 1536, 512, vtb);
        attn_mfma<<<dim3(Ldim/64, N_HEADS, Bdim), 256, 0, stream>>>(qk, vtb, obf);
        // tmp = o @ wo + bo  (8192 x 512 x 512), bf16 out
        gemm_bf16<1,0><<<256, 256, 0, stream>>>(obf, 512, oT + (size_t)i*512*512, 512,
                                                bo + i*512, tmp, 512, 4, 512, 512, nullptr);
        ln_kernel<<<ROWS/4, 256, 0, stream>>>(x, tmp, ln2_g + i*512, ln2_b + i*512, xbf);
    }
    proj_kernel<<<ROWS/4, 256, 0, stream>>>(x, proj_w, proj_b, out);
}